// Round 22
// baseline (236.232 us; speedup 1.0000x reference)
//
#include <hip/hip_runtime.h>
#include <math.h>

#define NHW   9216     // 96*96
#define NROWS 36864    // NHW*4

typedef _Float16 f16;
typedef _Float16 f16x8 __attribute__((ext_vector_type(8)));
typedef float    f32x4 __attribute__((ext_vector_type(4)));

// fast transcendentals (hardware v_exp_f32 / v_log_f32; rel err ~1e-5, fine vs thr 10.3)
__device__ __forceinline__ float fexpf(float x) { return __expf(x); }
__device__ __forceinline__ float flogf(float x) { return __logf(x); }

__device__ __forceinline__ float softplusf(float x) {
    return fmaxf(x, 0.f) + log1pf(fexpf(-fabsf(x)));
}

// LDS-only barrier: global loads into private VGPRs stay in flight across it.
__device__ __forceinline__ void barrier_lgkm() {
    __builtin_amdgcn_sched_barrier(0);
    asm volatile("s_waitcnt lgkmcnt(0)" ::: "memory");
    __builtin_amdgcn_s_barrier();
    __builtin_amdgcn_sched_barrier(0);
}

// ---------------- knots helper ----------------
__device__ __forceinline__ void knots8(const float* __restrict__ u, float* c, float* w) {
    float mx = u[0];
    #pragma unroll
    for (int k = 1; k < 8; ++k) mx = fmaxf(mx, u[k]);
    float e[8]; float s = 0.f;
    #pragma unroll
    for (int k = 0; k < 8; ++k) { e[k] = fexpf(u[k] - mx); s += e[k]; }
    float inv = 1.f / s;
    c[0] = -3.f;
    float cum = 0.f;
    #pragma unroll
    for (int k = 0; k < 8; ++k) {
        float v = 0.001f + 0.992f * e[k] * inv;
        cum += v;
        c[k + 1] = cum * 6.f - 3.f;
    }
    c[8] = 3.f;
    #pragma unroll
    for (int k = 0; k < 8; ++k) w[k] = c[k + 1] - c[k];
}

// ---------------- merged setup kernel: snorm | pack | prep ----------------
// blocks [0,2304): snorm tiles; [2304,5049): pack (flat 702496 elems);
// [5049,5123): prep fragment work (each recomputes Mlu in LDS); block 5123: idk+luc.
__global__ __launch_bounds__(256) void setup_kernel(
    const float* __restrict__ x,
    const float* __restrict__ sp_bW1, const float* __restrict__ sp_bW2,
    const float* __restrict__ made_bW1, const float* __restrict__ made_bW2,
    const float* __restrict__ sp_Wout, const float* __restrict__ made_Wout,
    const float* __restrict__ sp_Win, const float* __restrict__ made_W0,
    const float* __restrict__ sp_bCW, const float* __restrict__ made_ctxW,
    const float* __restrict__ made_bCW,
    const float* __restrict__ sp_bin, const float* __restrict__ sp_bCb,
    const float* __restrict__ made_ctxb, const float* __restrict__ made_b0,
    const float* __restrict__ made_bCb,
    const float* __restrict__ enc_W1, const float* __restrict__ enc_b1,
    const float* __restrict__ enc_W2, const float* __restrict__ enc_b2,
    const float* __restrict__ sp_uw, const float* __restrict__ sp_uh,
    const float* __restrict__ sp_ud,
    const float* __restrict__ lu_lower, const float* __restrict__ lu_upper,
    const float* __restrict__ lu_udiag, const float* __restrict__ lu_bias,
    const int*   __restrict__ lu_perm,
    float* __restrict__ z,
    f16* __restrict__ fW1f, f16* __restrict__ fW2f,
    f16* __restrict__ mW1f, f16* __restrict__ mW2f,
    f16* __restrict__ fWoutf, f16* __restrict__ mWoutf,
    f16* __restrict__ minf,
    f16* __restrict__ cfrag, float* __restrict__ cpb,
    f16* __restrict__ encW1f, f16* __restrict__ encW2f, float* __restrict__ epb,
    f16* __restrict__ weffF, f16* __restrict__ mlutF,
    float* __restrict__ beff, float* __restrict__ idk, float* __restrict__ luc)
{
    __shared__ float sS[33][34];
    __shared__ float sMlu[4][16][16];
    const int bid = blockIdx.x;
    const int t = threadIdx.x;

    if (bid < 2304) {
        const int bs   = bid / 36;
        const int tile = bid % 36;
        const int ti = tile / 6, tj = tile % 6;
        const int i0 = ti * 16, j0 = tj * 16;
        const int b = bs >> 4, s = bs & 15;
        const float* xb = x + (size_t)(bs * 3) * 36864;
        for (int e = t; e < 33 * 33; e += 256) {
            int row = e / 33, col = e % 33;
            int hh = 2 * i0 - 1 + row, ww = 2 * j0 - 1 + col;
            float acc = 0.f;
            if (hh >= 0 && hh < 192 && ww >= 0 && ww < 192) {
                #pragma unroll
                for (int c = 0; c < 3; ++c) {
                    float v = xb[c * 36864 + hh * 192 + ww];
                    acc += v * v;
                }
            }
            sS[row][col] = acc;
        }
        __syncthreads();
        const int oi = t >> 4, oj = t & 15;
        float sum = 0.f;
        #pragma unroll
        for (int dr = 0; dr < 3; ++dr)
            #pragma unroll
            for (int dc = 0; dc < 3; ++dc)
                sum += sS[2 * oi + dr][2 * oj + dc];
        const int i = i0 + oi, j = j0 + oj;
        z[((size_t)(i * 96 + j) * 4 + b) * 16 + s] = sqrtf(sum);
        return;
    }

    if (bid < 5049) {
        int idx = (bid - 2304) * 256 + t;
        if (idx < 131072) {
            int e = idx;
            int mtx = e >> 14, f = e & 16383;
            int nt = f >> 11, ks = (f >> 9) & 3, l = (f >> 3) & 63, j = f & 7;
            int n = nt * 16 + (l & 15), k = ks * 32 + ((l >> 4) & 3) * 8 + j;
            fW1f[e] = (f16)sp_bW1[mtx * 16384 + n * 128 + k];
            return;
        }
        idx -= 131072;
        if (idx < 131072) {
            int e = idx;
            int mtx = e >> 14, f = e & 16383;
            int nt = f >> 11, ks = (f >> 9) & 3, l = (f >> 3) & 63, j = f & 7;
            int n = nt * 16 + (l & 15), k = ks * 32 + ((l >> 4) & 3) * 8 + j;
            fW2f[e] = (f16)sp_bW2[mtx * 16384 + n * 128 + k];
            return;
        }
        idx -= 131072;
        if (idx < 32768) {
            int e = idx;
            int mtx = e >> 14, f = e & 16383;
            int nt = f >> 11, ks = (f >> 9) & 3, l = (f >> 3) & 63, j = f & 7;
            int n = nt * 16 + (l & 15), k = ks * 32 + ((l >> 4) & 3) * 8 + j;
            mW1f[e] = ((n % 15) >= (k % 15)) ? (f16)made_bW1[mtx * 16384 + n * 128 + k] : (f16)0.f;
            return;
        }
        idx -= 32768;
        if (idx < 32768) {
            int e = idx;
            int mtx = e >> 14, f = e & 16383;
            int nt = f >> 11, ks = (f >> 9) & 3, l = (f >> 3) & 63, j = f & 7;
            int n = nt * 16 + (l & 15), k = ks * 32 + ((l >> 4) & 3) * 8 + j;
            mW2f[e] = ((n % 15) >= (k % 15)) ? (f16)made_bW2[mtx * 16384 + n * 128 + k] : (f16)0.f;
            return;
        }
        idx -= 32768;
        if (idx < 98304) {
            int e = idx;
            int s = e / 24576, f = e % 24576;
            int nt = f >> 11, ks = (f >> 9) & 3, l = (f >> 3) & 63, j = f & 7;
            int n = nt * 16 + (l & 15), k = ks * 32 + ((l >> 4) & 3) * 8 + j;
            fWoutf[e] = (n < 184) ? (f16)sp_Wout[s * 23552 + n * 128 + k] : (f16)0.f;
            return;
        }
        idx -= 98304;
        if (idx < 4096) {
            int f = idx;
            int nt = f >> 11, ks = (f >> 9) & 3, l = (f >> 3) & 63, j = f & 7;
            int n = nt * 16 + (l & 15), k = ks * 32 + ((l >> 4) & 3) * 8 + j;
            mWoutf[idx] = (((n & 15) > (k % 15)) && n < 32) ? (f16)made_Wout[n * 128 + k] : (f16)0.f;
            return;
        }
        idx -= 4096;
        if (idx < 4096) {
            int f = idx;
            int nt = f >> 9, l = (f >> 3) & 63, j = f & 7;
            int n = nt * 16 + (l & 15), k = ((l >> 4) & 3) * 8 + j;
            minf[idx] = (k < 16 && (n % 15) >= k) ? (f16)made_W0[n * 16 + k] : (f16)0.f;
            return;
        }
        idx -= 4096;
        if (idx < 245760) {
            int e = idx;
            int s = e / 49152, f = e % 49152;
            int nt = f >> 11, ks = (f >> 9) & 3, l = (f >> 3) & 63, j = f & 7;
            int n = nt * 16 + (l & 15), k = ks * 32 + ((l >> 4) & 3) * 8 + j;
            float v;
            if (s < 4) {
                if (n < 128)      v = sp_Win[s * 17408 + n * 136 + 8 + k];
                else if (n < 256) v = sp_bCW[(size_t)(s * 2 + 0) * 16384 + (n - 128) * 128 + k];
                else              v = sp_bCW[(size_t)(s * 2 + 1) * 16384 + (n - 256) * 128 + k];
            } else {
                if (n < 128)      v = made_ctxW[n * 128 + k];
                else if (n < 256) v = made_bCW[(n - 128) * 128 + k];
                else              v = made_bCW[16384 + (n - 256) * 128 + k];
            }
            cfrag[e] = (f16)v;
            return;
        }
        idx -= 245760;
        if (idx < 1920) {
            int e = idx;
            int s = e / 384, n = e % 384;
            float v;
            if (s < 4) {
                if (n < 128)      v = sp_bin[s * 128 + n];
                else if (n < 256) v = sp_bCb[(s * 2 + 0) * 128 + (n - 128)];
                else              v = sp_bCb[(s * 2 + 1) * 128 + (n - 256)];
            } else {
                if (n < 128)      v = made_ctxb[n] + made_b0[n];
                else if (n < 256) v = made_bCb[n - 128];
                else              v = made_bCb[128 + (n - 256)];
            }
            cpb[e] = v;
            return;
        }
        idx -= 1920;
        if (idx < 16384) {
            int f = idx;
            int nt = f >> 11, ks = (f >> 9) & 3, l = (f >> 3) & 63, j = f & 7;
            int n = nt * 16 + (l & 15), k = ks * 32 + ((l >> 4) & 3) * 8 + j;
            encW1f[idx] = (f16)enc_W1[n * 128 + k];
            return;
        }
        idx -= 16384;
        if (idx < 4096) {
            int f = idx;
            int nt = f >> 11, ks = (f >> 9) & 3, l = (f >> 3) & 63, j = f & 7;
            int n = nt * 16 + (l & 15), k = ks * 32 + ((l >> 4) & 3) * 8 + j;
            encW2f[idx] = (n < 32) ? (f16)enc_W2[n * 128 + k] : (f16)0.f;
            return;
        }
        idx -= 4096;
        if (idx < 160) {
            epb[idx] = (idx < 128) ? enc_b1[idx] : enc_b2[idx - 128];
        }
        return;
    }

    if (bid == 5123) {
        if (t < 32) {
            int s = t >> 3, dim = t & 7;
            float* o = idk + (s * 8 + dim) * 48;
            float c[9], w[8];
            knots8(sp_uw + s * 64 + dim * 8, c, w);
            #pragma unroll
            for (int k = 0; k < 9; ++k) o[k] = c[k];
            #pragma unroll
            for (int k = 0; k < 8; ++k) o[9 + k] = w[k];
            knots8(sp_uh + s * 64 + dim * 8, c, w);
            #pragma unroll
            for (int k = 0; k < 9; ++k) o[17 + k] = c[k];
            #pragma unroll
            for (int k = 0; k < 8; ++k) o[26 + k] = w[k];
            o[34] = 1.f; o[42] = 1.f;
            #pragma unroll
            for (int k = 0; k < 7; ++k) o[35 + k] = 0.001f + softplusf(sp_ud[s * 56 + dim * 7 + k]);
        } else if (t == 32) {
            float c0 = 0.f;
            for (int k = 0; k < 64; ++k)
                c0 += flogf(softplusf(lu_udiag[k]) + 0.001f);
            luc[0] = c0;
        }
        return;
    }

    // ---- prep fragment blocks [5049,5123) ----
    {
        if (t < 64) {
            int s = t >> 4, d = t & 15;
            const float* L  = lu_lower + s * 256;
            const float* U  = lu_upper + s * 256;
            const float* ud = lu_udiag + s * 16;
            const int*   pm = lu_perm + s * 16;
            for (int c = 0; c < 16; ++c) {
                float m = 0.f;
                if (c > d)       m += U[d * 16 + c];
                else if (c == d) m += softplusf(ud[d]) + 0.001f;
                for (int e = 0; e < d && e <= c; ++e) {
                    float u = (c > e) ? U[e * 16 + c] : (softplusf(ud[e]) + 0.001f);
                    m += L[d * 16 + e] * u;
                }
                sMlu[s][d][pm[c]] = m;
            }
        }
        __syncthreads();
        int idx = (bid - 5049) * 256 + t;
        if (idx < 16384) {
            int e = idx;
            int s = e >> 12, f = e & 4095;
            int nt = f >> 9, l = (f >> 3) & 63, j = f & 7;
            int n = nt * 16 + (l & 15), k = ((l >> 4) & 3) * 8 + j;
            float v = 0.f;
            if (k < 16) {
                #pragma unroll
                for (int p = 0; p < 8; ++p)
                    v += sMlu[s][2 * p][k] * sp_Win[s * 17408 + n * 136 + p];
            }
            weffF[e] = (f16)v;
        } else if (idx < 18432) {
            int e = idx - 16384;
            int s = e >> 9, f = e & 511;
            int l = f >> 3, j = f & 7;
            int n = l & 15, k = (l >> 4) * 8 + j;
            mlutF[e] = (k < 16) ? (f16)sMlu[s][n][k] : (f16)0.f;
        } else if (idx < 18944) {
            int e = idx - 18432;
            int s = e >> 7, n = e & 127;
            float v = 0.f;
            #pragma unroll
            for (int p = 0; p < 8; ++p)
                v += lu_bias[s * 16 + 2 * p] * sp_Win[s * 17408 + n * 136 + p];
            beff[e] = v;
        }
        return;
    }
}

// ---------------- ctx-chain MFMA: 2 slices per block ----------------
__global__ __launch_bounds__(256) void ctx_mfma(
    const f16* __restrict__ cfrag,
    const float* __restrict__ cpb,
    const f16* __restrict__ encW1f, const f16* __restrict__ encW2f,
    const float* __restrict__ epb,
    f16* __restrict__ ctxoutf, float* __restrict__ ehw)
{
    __shared__ alignas(16) f16 cS[16][136];
    __shared__ alignas(16) f16 hS[16][136];
    const int tid = threadIdx.x, w = tid >> 6, l = tid & 63;
    const int m0 = blockIdx.x * 16;
    const int sy = blockIdx.y;
    const int lr = l & 15, lq = l >> 4;
    #pragma unroll
    for (int it = 0; it < 2; ++it) {
        int e = tid + it * 256;
        int r = e >> 5, c4 = (e & 31) * 4;
        int hw = m0 + r;
        int ii = hw / 96, jj = hw % 96;
        #pragma unroll
        for (int q = 0; q < 4; ++q) {
            int c = c4 + q;
            int pos = (c < 64) ? ii : jj;
            int cc = c & 63;
            int k = cc >> 1;
            float invf = exp2f((float)k * -0.4152410118609203f);  // 10000^(-k/32)
            float v = (float)pos * invf;
            cS[r][c] = (f16)((cc & 1) ? cosf(v) : sinf(v));
        }
    }
    __syncthreads();
    const f32x4 vzero = {0.f, 0.f, 0.f, 0.f};
    #pragma unroll
    for (int sub = 0; sub < 2; ++sub) {
        const int s = sy * 2 + sub;
        if (s < 5) {
            f32x4 acc[6];
            #pragma unroll
            for (int q = 0; q < 6; ++q) acc[q] = vzero;
            const f16* wb = cfrag + (size_t)s * 49152;
            #pragma unroll
            for (int ks = 0; ks < 4; ++ks) {
                f16x8 a = *(const f16x8*)&cS[lr][ks * 32 + lq * 8];
                #pragma unroll
                for (int q = 0; q < 6; ++q) {
                    int g = w * 6 + q;
                    f16x8 b = *(const f16x8*)(wb + (size_t)((g * 4 + ks) * 64 + l) * 8);
                    acc[q] = __builtin_amdgcn_mfma_f32_16x16x32_f16(a, b, acc[q], 0, 0, 0);
                }
            }
            #pragma unroll
            for (int q = 0; q < 6; ++q) {
                int g = w * 6 + q, n = g * 16 + lr;
                float bias = cpb[s * 384 + n];
                #pragma unroll
                for (int r = 0; r < 4; ++r) {
                    float val = acc[q][r] + bias;
                    if (n >= 128) val = 1.f / (1.f + fexpf(-val));
                    ctxoutf[(size_t)s * NHW * 384 + (size_t)(m0 + lq * 4 + r) * 384 + n] = (f16)val;
                }
            }
        } else {
            f32x4 acc0 = vzero, acc1 = vzero;
            #pragma unroll
            for (int ks = 0; ks < 4; ++ks) {
                f16x8 a = *(const f16x8*)&cS[lr][ks * 32 + lq * 8];
                f16x8 b0 = *(const f16x8*)(encW1f + (((w * 2 + 0) * 4 + ks) * 64 + l) * 8);
                f16x8 b1 = *(const f16x8*)(encW1f + (((w * 2 + 1) * 4 + ks) * 64 + l) * 8);
                acc0 = __builtin_amdgcn_mfma_f32_16x16x32_f16(a, b0, acc0, 0, 0, 0);
                acc1 = __builtin_amdgcn_mfma_f32_16x16x32_f16(a, b1, acc1, 0, 0, 0);
            }
            {
                int n0 = (w * 2 + 0) * 16 + lr, n1 = (w * 2 + 1) * 16 + lr;
                float bi0 = epb[n0], bi1 = epb[n1];
                #pragma unroll
                for (int r = 0; r < 4; ++r) {
                    float v0 = acc0[r] + bi0, v1 = acc1[r] + bi1;
                    hS[lq * 4 + r][n0] = (f16)(v0 / (1.f + fexpf(-v0)));
                    hS[lq * 4 + r][n1] = (f16)(v1 / (1.f + fexpf(-v1)));
                }
            }
            __syncthreads();
            if (w < 2) {
                f32x4 po = vzero;
                #pragma unroll
                for (int ks = 0; ks < 4; ++ks) {
                    f16x8 a = *(const f16x8*)&hS[lr][ks * 32 + lq * 8];
                    f16x8 b = *(const f16x8*)(encW2f + ((w * 4 + ks) * 64 + l) * 8);
                    po = __builtin_amdgcn_mfma_f32_16x16x32_f16(a, b, po, 0, 0, 0);
                }
                int n = w * 16 + lr;
                float bias = epb[128 + n];
                #pragma unroll
                for (int r = 0; r < 4; ++r)
                    ehw[(size_t)(m0 + lq * 4 + r) * 32 + n] = po[r] + bias;
            }
        }
    }
}

// ---------------- rational-quadratic spline ----------------
__device__ __forceinline__ void rqs_core(float x, const float* cw, const float* wd,
                                         const float* ch, const float* hg, const float* dd,
                                         float& y, float& ld) {
    bool inside = (x >= -3.f) && (x <= 3.f);
    float xc = fminf(fmaxf(x, -3.f), 3.f);
    float cwk = cw[0], wk = wd[0], chk = ch[0], hk = hg[0], d0 = dd[0], d1 = dd[1];
    #pragma unroll
    for (int k = 1; k < 8; ++k) {
        if (xc >= cw[k]) { cwk = cw[k]; wk = wd[k]; chk = ch[k]; hk = hg[k]; d0 = dd[k]; d1 = dd[k + 1]; }
    }
    float dl = hk / wk;
    float th = (xc - cwk) / wk;
    float t1 = th * (1.f - th);
    float den = dl + (d0 + d1 - 2.f * dl) * t1;
    float yy = chk + hk * (dl * th * th + d0 * t1) / den;
    float om = 1.f - th;
    float dnum = dl * dl * (d1 * th * th + 2.f * dl * t1 + d0 * om * om);
    float lld = flogf(dnum) - 2.f * flogf(den);
    y  = inside ? yy : x;
    ld = inside ? lld : 0.f;
}

__device__ __forceinline__ void rqs1(float x,
                                     const float* __restrict__ uw,
                                     const float* __restrict__ uh,
                                     const float* __restrict__ ud,
                                     float& y, float& ld) {
    float cw[9], wd[8], ch[9], hg[8], dd[9];
    knots8(uw, cw, wd);
    knots8(uh, ch, hg);
    dd[0] = 1.f; dd[8] = 1.f;
    #pragma unroll
    for (int k = 0; k < 7; ++k) dd[k + 1] = 0.001f + softplusf(ud[k]);
    rqs_core(x, cw, wd, ch, hg, dd, y, ld);
}

__device__ __forceinline__ void rqs1_pre(float x, const float* __restrict__ kn,
                                         float& y, float& ld) {
    float cw[9], wd[8], ch[9], hg[8], dd[9];
    #pragma unroll
    for (int k = 0; k < 9; ++k) cw[k] = kn[k];
    #pragma unroll
    for (int k = 0; k < 8; ++k) wd[k] = kn[9 + k];
    #pragma unroll
    for (int k = 0; k < 9; ++k) ch[k] = kn[17 + k];
    #pragma unroll
    for (int k = 0; k < 8; ++k) hg[k] = kn[26 + k];
    #pragma unroll
    for (int k = 0; k < 9; ++k) dd[k] = kn[34 + k];
    rqs_core(x, cw, wd, ch, hg, dd, y, ld);
}

// ---------------- prefetch helpers ----------------
__device__ __forceinline__ void load8(const f16* __restrict__ w, int nt0, int l,
                                      f16x8 B[8]) {
    #pragma unroll
    for (int q = 0; q < 2; ++q)
        #pragma unroll
        for (int ks = 0; ks < 4; ++ks)
            B[q * 4 + ks] = *(const f16x8*)(w + (nt0 + q) * 2048 + ks * 512 + l * 8);
}

// two-tile GEMM: shared B-frags, A-frags from both tiles' LDS (stride-templated)
template<int S>
__device__ __forceinline__ void gemm16(const f16 (*__restrict__ SA)[S],
                                       const f16 (*__restrict__ SB)[S],
                                       int lr, int lqw, const f16x8 B[8],
                                       f32x4& aA0, f32x4& aA1, f32x4& aB0, f32x4& aB1) {
    __builtin_amdgcn_s_setprio(1);
    #pragma unroll
    for (int ks = 0; ks < 4; ++ks) {
        f16x8 aA = *(const f16x8*)&SA[lr][ks * 32 + lqw * 8];
        f16x8 aB = *(const f16x8*)&SB[lr][ks * 32 + lqw * 8];
        aA0 = __builtin_amdgcn_mfma_f32_16x16x32_f16(aA, B[ks], aA0, 0, 0, 0);
        aB0 = __builtin_amdgcn_mfma_f32_16x16x32_f16(aB, B[ks], aB0, 0, 0, 0);
        aA1 = __builtin_amdgcn_mfma_f32_16x16x32_f16(aA, B[4 + ks], aA1, 0, 0, 0);
        aB1 = __builtin_amdgcn_mfma_f32_16x16x32_f16(aB, B[4 + ks], aB1, 0, 0, 0);
    }
    __builtin_amdgcn_s_setprio(0);
}

// ---------------- merged pipeline: TWO 16-row tiles per block ----------------
// LDS diet: uS and pS were never live simultaneously -> one union buffer uS[2][16][196].
// 29.8 KB LDS -> 5 blocks/CU; launch_bounds(256,5) keeps VGPR <= 102 for 5 waves/SIMD.
__global__ __launch_bounds__(256, 5) void mega_all(
    const float* __restrict__ zg,
    const f16*  __restrict__ ctxoutf,   // [5][9216][384]
    const f16*  __restrict__ weffF,     // [4][4096]
    const f16*  __restrict__ mlutF,     // [4][512]
    const float* __restrict__ beffv,    // [4][128]
    const f16*  __restrict__ minf,      // [4096]
    const f16*  __restrict__ fW1f,      // [4][2][16384]
    const f16*  __restrict__ fW2f,
    const f16*  __restrict__ mW1f,      // [2][16384]
    const f16*  __restrict__ mW2f,
    const f16*  __restrict__ fWoutf,    // [4][24576]
    const f16*  __restrict__ mWoutf,    // [4096]
    const float* __restrict__ sp_bb1,   // [4][2][128]
    const float* __restrict__ sp_bb2,
    const float* __restrict__ made_bb1, // [2][128]
    const float* __restrict__ made_bb2,
    const float* __restrict__ sp_bout,  // [4][184]
    const float* __restrict__ made_bout,// [32]
    const float* __restrict__ lu_bias,  // [4][16]
    const float* __restrict__ idk,      // [4][8][48]
    const float* __restrict__ luc,      // [1]
    const float* __restrict__ ehw,      // [9216][32]
    float* __restrict__ out)            // [4][9216]
{
    __shared__ alignas(16) f16 tS[2][16][136];
    __shared__ alignas(16) f16 uS[2][16][196];   // union: residual hidden (cols<128) / WOUT out (cols<196)
    __shared__ alignas(16) f16 zS[2][16][32];
    __shared__ float zlu[2][16][17];
    __shared__ float zO[2][16][17];
    __shared__ float ldS[2][16][17];
    const int tid = threadIdx.x;
    const int w   = tid >> 6;
    const int l   = tid & 63;
    const int lr  = l & 15;
    const int lqw = l >> 4;
    const int m0  = blockIdx.x * 32;
    const int hwA = (m0 >> 2) + lqw;
    const int hwB = hwA + 4;
    const int nt0 = w * 2;
    const f32x4 vzero = {0.f, 0.f, 0.f, 0.f};

    #pragma unroll
    for (int it = 0; it < 2; ++it) {
        int e = tid + it * 256;
        int rr = e >> 4, d2 = e & 15;
        int t2 = rr >> 4, r2 = rr & 15;
        zS[t2][r2][d2] = (f16)zg[(size_t)(m0 + rr) * 16 + d2];
        zS[t2][r2][16 + d2] = (f16)0.f;
    }
    float luc0 = luc[0];
    float ldA = 0.f, ldB = 0.f;

    f16x8 B[8];
    f16x8 bml;
    B[0] = *(const f16x8*)(weffF + 3 * 4096 + ((nt0 + 0) * 64 + l) * 8);
    B[1] = *(const f16x8*)(weffF + 3 * 4096 + ((nt0 + 1) * 64 + l) * 8);
    bml  = *(const f16x8*)(mlutF + 3 * 512 + l * 8);
    barrier_lgkm();

    const int n0q = (w + 0) * 16 + lr, n1q = (w + 4) * 16 + lr, n2q = (w + 8) * 16 + lr;

    float tRA[2][4], tRB[2][4];

    for (int i = 3; i >= 0; --i) {
        const f16* cbA = ctxoutf + (size_t)i * NHW * 384 + (size_t)hwA * 384;
        const f16* cbB = ctxoutf + (size_t)i * NHW * 384 + (size_t)hwB * 384;
        // ---- IN ----
        {
            f16x8 aA = *(const f16x8*)&zS[0][lr][lqw * 8];
            f16x8 aB = *(const f16x8*)&zS[1][lr][lqw * 8];
            if (w < 2) {
                float bl = lu_bias[i * 16 + lr];
                f32x4 c = {bl, bl, bl, bl};
                c = __builtin_amdgcn_mfma_f32_16x16x32_f16(w == 0 ? aA : aB, bml, c, 0, 0, 0);
                #pragma unroll
                for (int r = 0; r < 4; ++r)
                    zlu[w][lqw * 4 + r][lr] = c[r];
            }
            #pragma unroll
            for (int t = 0; t < 2; ++t) {
                int n = (nt0 + t) * 16 + lr;
                float bf = beffv[i * 128 + n];
                float ciA = (float)cbA[n] + bf;
                float ciB = (float)cbB[n] + bf;
                f32x4 cA = {ciA, ciA, ciA, ciA};
                f32x4 cB = {ciB, ciB, ciB, ciB};
                cA = __builtin_amdgcn_mfma_f32_16x16x32_f16(aA, B[t], cA, 0, 0, 0);
                cB = __builtin_amdgcn_mfma_f32_16x16x32_f16(aB, B[t], cB, 0, 0, 0);
                #pragma unroll
                for (int r = 0; r < 4; ++r) {
                    tRA[t][r] = cA[r];
                    tRB[t][r] = cB[r];
                    tS[0][lqw * 4 + r][n] = (f16)fmaxf(cA[r], 0.f);
                    tS[1][lqw * 4 + r][n] = (f16)fmaxf(cB[r], 0.f);
                }
            }
            load8(fW1f + (size_t)i * 32768, nt0, l, B);
        }
        barrier_lgkm();
        // ---- residual blocks ----
        #pragma unroll
        for (int blk = 0; blk < 2; ++blk) {
            // W1
            {
                f32x4 aA0 = vzero, aA1 = vzero, aB0 = vzero, aB1 = vzero;
                gemm16<136>(tS[0], tS[1], lr, lqw, B, aA0, aA1, aB0, aB1);
                load8(fW2f + (size_t)i * 32768 + blk * 16384, nt0, l, B);
                const float* bb1p = sp_bb1 + i * 256 + blk * 128;
                float bi0 = bb1p[(nt0 + 0) * 16 + lr];
                float bi1 = bb1p[(nt0 + 1) * 16 + lr];
                #pragma unroll
                for (int r = 0; r < 4; ++r) {
                    uS[0][lqw * 4 + r][(nt0 + 0) * 16 + lr] = (f16)fmaxf(aA0[r] + bi0, 0.f);
                    uS[0][lqw * 4 + r][(nt0 + 1) * 16 + lr] = (f16)fmaxf(aA1[r] + bi1, 0.f);
                    uS[1][lqw * 4 + r][(nt0 + 0) * 16 + lr] = (f16)fmaxf(aB0[r] + bi0, 0.f);
                    uS[1][lqw * 4 + r][(nt0 + 1) * 16 + lr] = (f16)fmaxf(aB1[r] + bi1, 0.f);
                }
            }
            barrier_lgkm();
            // W2
            {
                f32x4 aA0 = vzero, aA1 = vzero, aB0 = vzero, aB1 = vzero;
                gemm16<196>(uS[0], uS[1], lr, lqw, B, aA0, aA1, aB0, aB1);
                if (blk == 0) load8(fW1f + (size_t)i * 32768 + 16384, nt0, l, B);
                else {
                    const f16* wo = fWoutf + (size_t)i * 24576;
                    #pragma unroll
                    for (int t2 = 0; t2 < 2; ++t2)
                        #pragma unroll
                        for (int ks = 0; ks < 4; ++ks)
                            B[t2 * 4 + ks] = *(const f16x8*)(wo + (w + t2 * 4) * 2048 + ks * 512 + l * 8);
                }
                const float* bb2p = sp_bb2 + i * 256 + blk * 128;
                float bi0 = bb2p[(nt0 + 0) * 16 + lr];
                float bi1 = bb2p[(nt0 + 1) * 16 + lr];
                float gA0 = (float)cbA[128 + blk * 128 + (nt0 + 0) * 16 + lr];
                float gA1 = (float)cbA[128 + blk * 128 + (nt0 + 1) * 16 + lr];
                float gB0 = (float)cbB[128 + blk * 128 + (nt0 + 0) * 16 + lr];
                float gB1 = (float)cbB[128 + blk * 128 + (nt0 + 1) * 16 + lr];
                #pragma unroll
                for (int r = 0; r < 4; ++r) {
                    tRA[0][r] += (aA0[r] + bi0) * gA0;
                    tRA[1][r] += (aA1[r] + bi1) * gA1;
                    tRB[0][r] += (aB0[r] + bi0) * gB0;
                    tRB[1][r] += (aB1[r] + bi1) * gB1;
                    if (blk == 0) {
                        tS[0][lqw * 4 + r][(nt0 + 0) * 16 + lr] = (f16)fmaxf(tRA[0][r], 0.f);
                        tS[0][lqw * 4 + r][(nt0 + 1) * 16 + lr] = (f16)fmaxf(tRA[1][r], 0.f);
                        tS[1][lqw * 4 + r][(nt0 + 0) * 16 + lr] = (f16)fmaxf(tRB[0][r], 0.f);
                        tS[1][lqw * 4 + r][(nt0 + 1) * 16 + lr] = (f16)fmaxf(tRB[1][r], 0.f);
                    } else {
                        tS[0][lqw * 4 + r][(nt0 + 0) * 16 + lr] = (f16)tRA[0][r];
                        tS[0][lqw * 4 + r][(nt0 + 1) * 16 + lr] = (f16)tRA[1][r];
                        tS[1][lqw * 4 + r][(nt0 + 0) * 16 + lr] = (f16)tRB[0][r];
                        tS[1][lqw * 4 + r][(nt0 + 1) * 16 + lr] = (f16)tRB[1][r];
                    }
                }
            }
            barrier_lgkm();
        }
        // ---- WOUT -> uS (union; both tiles; B holds nt w, w+4) ----
        {
            f32x4 pA0 = vzero, pA1 = vzero, pA2 = vzero;
            f32x4 pB0 = vzero, pB1 = vzero, pB2 = vzero;
            const f16* wo = fWoutf + (size_t)i * 24576;
            __builtin_amdgcn_s_setprio(1);
            #pragma unroll
            for (int ks = 0; ks < 4; ++ks) {
                f16x8 aA = *(const f16x8*)&tS[0][lr][ks * 32 + lqw * 8];
                f16x8 aB = *(const f16x8*)&tS[1][lr][ks * 32 + lqw * 8];
                pA0 = __builtin_amdgcn_mfma_f32_16x16x32_f16(aA, B[ks], pA0, 0, 0, 0);
                pB0 = __builtin_amdgcn_mfma_f32_16x16x32_f16(aB, B[ks], pB0, 0, 0, 0);
                pA1 = __builtin_amdgcn_mfma_f32_16x16x32_f16(aA, B[4 + ks], pA1, 0, 0, 0);
                pB1 = __builtin_amdgcn_mfma_f32_16x16x32_f16(aB, B[4 + ks], pB1, 0, 0, 0);
                f16x8 b2 = *(const f16x8*)(wo + (w + 8) * 2048 + ks * 512 + l * 8);
                pA2 = __builtin_amdgcn_mfma_f32_16x16x32_f16(aA, b2, pA2, 0, 0, 0);
                pB2 = __builtin_amdgcn_mfma_f32_16x16x32_f16(aB, b2, pB2, 0, 0, 0);
            }
            __builtin_amdgcn_s_setprio(0);
            if (i > 0) {
                B[0] = *(const f16x8*)(weffF + (i - 1) * 4096 + ((nt0 + 0) * 64 + l) * 8);
                B[1] = *(const f16x8*)(weffF + (i - 1) * 4096 + ((nt0 + 1) * 64 + l) * 8);
                bml  = *(const f16x8*)(mlutF + (i - 1) * 512 + l * 8);
            } else {
                B[0] = *(const f16x8*)(minf + ((nt0 + 0) * 64 + l) * 8);
                B[1] = *(const f16x8*)(minf + ((nt0 + 1) * 64 + l) * 8);
            }
            const float* bo = sp_bout + i * 184;
            float b0v = bo[n0q], b1v = bo[n1q];
            float b2v = (n2q < 184) ? bo[n2q] : 0.f;
            #pragma unroll
            for (int r = 0; r < 4; ++r) {
                uS[0][lqw * 4 + r][n0q] = (f16)(pA0[r] + b0v);
                uS[1][lqw * 4 + r][n0q] = (f16)(pB0[r] + b0v);
                uS[0][lqw * 4 + r][n1q] = (f16)(pA1[r] + b1v);
                uS[1][lqw * 4 + r][n1q] = (f16)(pB1[r] + b1v);
                if (n2q < 184) {
                    uS[0][lqw * 4 + r][n2q] = (f16)(pA2[r] + b2v);
                    uS[1][lqw * 4 + r][n2q] = (f16)(pB2[r] + b2v);
                }
            }
        }
        barrier_lgkm();
        // ---- SPLINE (load-balanced: each 16-thread group does 1 tr + 1 id) ----
        {
            const int g = tid >> 4, rw = tid & 15;
            const int dim = (g < 8) ? g : (g - 8);
            const int trT = (g < 8) ? 0 : 1;   // tile for tr
            const int idT = 1 - trT;           // tile for id
            float y, ldv;
            {
                const float is = 0.08838834764831845f;
                float uw[8], uh[8], udv[7];
                const f16* pr = &uS[trT][rw][dim * 23];
                #pragma unroll
                for (int k = 0; k < 8; ++k) { uw[k] = (float)pr[k] * is; uh[k] = (float)pr[8 + k] * is; }
                #pragma unroll
                for (int k = 0; k < 7; ++k) udv[k] = (float)pr[16 + k];
                float xx = zlu[trT][rw][2 * dim + 1];
                rqs1(xx, uw, uh, udv, y, ldv);
                zO[trT][rw][2 * dim + 1] = y;
                zS[trT][rw][2 * dim + 1] = (f16)y;
                if (trT == 0) ldA += ldv; else ldB += ldv;
            }
            {
                float xx = zlu[idT][rw][2 * dim];
                rqs1_pre(xx, idk + i * 384 + dim * 48, y, ldv);
                zO[idT][rw][2 * dim] = y;
                zS[idT][rw][2 * dim] = (f16)y;
                if (idT == 0) ldA += ldv; else ldB += ldv;
            }
        }
        barrier_lgkm();
    }

    // publish logq partials
    ldS[0][tid >> 4][tid & 15] = ldA;
    ldS[1][tid >> 4][tid & 15] = ldB;

    // ---- MADE stage ----
    {
        const f16* cbA = ctxoutf + (size_t)4 * NHW * 384 + (size_t)hwA * 384;
        const f16* cbB = ctxoutf + (size_t)4 * NHW * 384 + (size_t)hwB * 384;
        {
            f16x8 aA = *(const f16x8*)&zS[0][lr][lqw * 8];
            f16x8 aB = *(const f16x8*)&zS[1][lr][lqw * 8];
            #pragma unroll
            for (int t = 0; t < 2; ++t) {
                int n = (nt0 + t) * 16 + lr;
                float thA = (float)cbA[n];
                float thB = (float)cbB[n];
                f32x4 cA = {thA, thA, thA, thA};
                f32x4 cB = {thB, thB, thB, thB};
                cA = __builtin_amdgcn_mfma_f32_16x16x32_f16(aA, B[t], cA, 0, 0, 0);
                cB = __builtin_amdgcn_mfma_f32_16x16x32_f16(aB, B[t], cB, 0, 0, 0);
                #pragma unroll
                for (int r = 0; r < 4; ++r) {
                    tRA[t][r] = cA[r];
                    tRB[t][r] = cB[r];
                    tS[0][lqw * 4 + r][n] = (f16)fmaxf(cA[r], 0.f);
                    tS[1][lqw * 4 + r][n] = (f16)fmaxf(cB[r], 0.f);
                }
            }
            load8(mW1f, nt0, l, B);
        }
        barrier_lgkm();
        #pragma unroll
        for (int blk = 0; blk < 2; ++blk) {
            {
                f32x4 aA0 = vzero, aA1 = vzero, aB0 = vzero, aB1 = vzero;
                gemm16<136>(tS[0], tS[1], lr, lqw, B, aA0, aA1, aB0, aB1);
                load8(mW2f + blk * 16384, nt0, l, B);
                const float* bb1p = made_bb1 + blk * 128;
                float bi0 = bb1p[(nt0 + 0) * 16 + lr];
                float bi1 = bb1p[(nt0 + 1) * 16 + lr];
                #pragma unroll
                for (int r = 0; r < 4; ++r) {
                    uS[0][lqw * 4 + r][(nt0 + 0) * 16 + lr] = (f16)fmaxf(aA0[r] + bi0, 0.f);
                    uS[0][lqw * 4 + r][(nt0 + 1) * 16 + lr] = (f16)fmaxf(aA1[r] + bi1, 0.f);
                    uS[1][lqw * 4 + r][(nt0 + 0) * 16 + lr] = (f16)fmaxf(aB0[r] + bi0, 0.f);
                    uS[1][lqw * 4 + r][(nt0 + 1) * 16 + lr] = (f16)fmaxf(aB1[r] + bi1, 0.f);
                }
            }
            barrier_lgkm();
            {
                f32x4 aA0 = vzero, aA1 = vzero, aB0 = vzero, aB1 = vzero;
                gemm16<196>(uS[0], uS[1], lr, lqw, B, aA0, aA1, aB0, aB1);
                if (blk == 0) load8(mW1f + 16384, nt0, l, B);
                const float* bb2p = made_bb2 + blk * 128;
                float bi0 = bb2p[(nt0 + 0) * 16 + lr];
                float bi1 = bb2p[(nt0 + 1) * 16 + lr];
                float gA0 = (float)cbA[128 + blk * 128 + (nt0 + 0) * 16 + lr];
                float gA1 = (float)cbA[128 + blk * 128 + (nt0 + 1) * 16 + lr];
                float gB0 = (float)cbB[128 + blk * 128 + (nt0 + 0) * 16 + lr];
                float gB1 = (float)cbB[128 + blk * 128 + (nt0 + 1) * 16 + lr];
                #pragma unroll
                for (int r = 0; r < 4; ++r) {
                    tRA[0][r] += (aA0[r] + bi0) * gA0;
                    tRA[1][r] += (aA1[r] + bi1) * gA1;
                    tRB[0][r] += (aB0[r] + bi0) * gB0;
                    tRB[1][r] += (aB1[r] + bi1) * gB1;
                    if (blk == 0) {
                        tS[0][lqw * 4 + r][(nt0 + 0) * 16 + lr] = (f16)fmaxf(tRA[0][r], 0.f);
                        tS[0][lqw * 4 + r][(nt0 + 1) * 16 + lr] = (f16)fmaxf(tRA[1][r], 0.f);
                        tS[1][lqw * 4 + r][(nt0 + 0) * 16 + lr] = (f16)fmaxf(tRB[0][r], 0.f);
                        tS[1][lqw * 4 + r][(nt0 + 1) * 16 + lr] = (f16)fmaxf(tRB[1][r], 0.f);
                    } else {
                        tS[0][lqw * 4 + r][(nt0 + 0) * 16 + lr] = (f16)tRA[0][r];
                        tS[0][lqw * 4 + r][(nt0 + 1) * 16 + lr] = (f16)tRA[1][r];
                        tS[1][lqw * 4 + r][(nt0 + 0) * 16 + lr] = (f16)tRB[0][r];
                        tS[1][lqw * 4 + r][(nt0 + 1) * 16 + lr] = (f16)tRB[1][r];
                    }
                }
            }
            barrier_lgkm();
        }
        // MADE Wout: waves 0-1 -> tile 0 (nt=w), waves 2-3 -> tile 1 (nt=w-2)
        {
            const int t2 = w >> 1, nt = w & 1;
            f32x4 po = vzero;
            #pragma unroll
            for (int ks = 0; ks < 4; ++ks) {
                f16x8 a = *(const f16x8*)&tS[t2][lr][ks * 32 + lqw * 8];
                f16x8 b = *(const f16x8*)(mWoutf + nt * 2048 + ks * 512 + l * 8);
                po = __builtin_amdgcn_mfma_f32_16x16x32_f16(a, b, po, 0, 0, 0);
            }
            int n = nt * 16 + lr;
            float bias = made_bout[n];
            #pragma unroll
            for (int r = 0; r < 4; ++r)
                uS[t2][lqw * 4 + r][n] = (f16)(po[r] + bias);
        }
    }
    barrier_lgkm();
    // ---- Gaussian head (both tiles) ----
    {
        const int rw = tid >> 4, d = tid & 15;
        #pragma unroll
        for (int t2 = 0; t2 < 2; ++t2) {
            const int gm = m0 + t2 * 16 + rw, hw = gm >> 2, b = gm & 3;
            float ar0 = (float)uS[t2][rw][2 * d];
            float ar1 = (float)uS[t2][rw][2 * d + 1];
            float s = softplusf(ar0) + 0.001f;
            float zn = s * zO[t2][rw][d] + ar1;
            float ls   = ehw[(size_t)hw * 32 + 16 + d];
            float mean = ehw[(size_t)hw * 32 + d];
            float diff = (zn - mean) * fexpf(-ls);
            float g = flogf(s) - ls - 0.5f * diff * diff + ldS[t2][d][rw];
            g += __shfl_xor(g, 1);
            g += __shfl_xor(g, 2);
            g += __shfl_xor(g, 4);
            g += __shfl_xor(g, 8);
            if (d == 0)
                out[(size_t)b * NHW + hw] = g + luc0 - 14.703016531274762f;
        }
    }
}

extern "C" void kernel_launch(void* const* d_in, const int* in_sizes, int n_in,
                              void* d_out, int out_size, void* d_ws, size_t ws_size,
                              hipStream_t stream) {
    (void)in_sizes; (void)n_in; (void)out_size; (void)ws_size;
    const float* x         = (const float*)d_in[0];
    const float* made_W0   = (const float*)d_in[1];
    const float* made_b0   = (const float*)d_in[2];
    const float* made_ctxW = (const float*)d_in[3];
    const float* made_ctxb = (const float*)d_in[4];
    const float* made_bW1  = (const float*)d_in[5];
    const float* made_bb1  = (const float*)d_in[6];
    const float* made_bW2  = (const float*)d_in[7];
    const float* made_bb2  = (const float*)d_in[8];
    const float* made_bCW  = (const float*)d_in[9];
    const float* made_bCb  = (const float*)d_in[10];
    const float* made_Wout = (const float*)d_in[11];
    const float* made_bout = (const float*)d_in[12];
    const float* sp_Win    = (const float*)d_in[13];
    const float* sp_bin    = (const float*)d_in[14];
    const float* sp_bW1    = (const float*)d_in[15];
    const float* sp_bb1    = (const float*)d_in[16];
    const float* sp_bW2    = (const float*)d_in[17];
    const float* sp_bb2    = (const float*)d_in[18];
    const float* sp_bCW    = (const float*)d_in[19];
    const float* sp_bCb    = (const float*)d_in[20];
    const float* sp_Wout   = (const float*)d_in[21];
    const float* sp_bout   = (const float*)d_in[22];
    const float* sp_uw     = (const float*)d_in[23];
    const float* sp_uh     = (const float*)d_in[24];
    const float* sp_ud     = (const float*)d_in[25];
    const float* lu_lower  = (const float*)d_in[26];
    const float* lu_upper  = (const float*)d_in[27];
    const float* lu_udiag  = (const float*)d_in[28];
    const float* lu_bias   = (const float*)d_in[29];
    const int*   lu_perm   = (const int*)d_in[30];
    const float* enc_W1    = (const float*)d_in[31];
    const float* enc_b1    = (const float*)d_in[32];
    const float* enc_W2    = (const float*)d_in[33];
    const float* enc_b2    = (const float*)d_in[34];
    float* out = (float*)d_out;

    float* ws      = (float*)d_ws;
    float* z       = ws;                               // 36864*16
    float* ehw     = z       + (size_t)NROWS * 16;     // 9216*32
    float* cpb     = ehw     + (size_t)NHW * 32;       // 5*384
    float* epb     = cpb     + 5 * 384;                // 160 (pad 192)
    float* idk     = epb     + 192;                    // 4*8*48
    float* beff    = idk     + 1536;                   // 4*128
    float* luc     = beff    + 512;                    // 1 (pad 16)
    f16*   ctxoutf = (f16*)(luc + 16);                 // 5*9216*384 f16
    f16*   fW1f    = ctxoutf + (size_t)5 * NHW * 384;  // 8*16384
    f16*   fW2f    = fW1f    + 8 * 16384;              // 8*16384
    f16*   mW1f    = fW2f    + 8 * 16384;              // 2*16384
    f16*   mW2f    = mW1f    + 2 * 16384;              // 2*16384
    f16*   fWoutf  = mW2f    + 2 * 16384;              // 4*24576
    f16*   mWoutf  = fWoutf  + 4 * 24576;              // 4096
    f16*   weffF   = mWoutf  + 4096;                   // 4*4096
    f16*   mlutF   = weffF   + 4 * 4096;               // 4*512
    f16*   minf    = mlutF   + 4 * 512;                // 4096
    f16*   encW1f  = minf    + 4096;                   // 16384
    f16*   encW2f  = encW1f  + 16384;                  // 4096
    f16*   cfrag   = encW2f  + 4096;                   // 5*49152

    dim3 B(256);
    setup_kernel<<<5124, B, 0, stream>>>(
        x,
        sp_bW1, sp_bW2, made_bW1, made_bW2, sp_Wout, made_Wout, sp_Win, made_W0,
        sp_bCW, made_ctxW, made_bCW, sp_bin, sp_bCb, made_ctxb, made_b0, made_bCb,
        enc_W1, enc_b1, enc_W2, enc_b2,
        sp_uw, sp_uh, sp_ud, lu_lower, lu_upper, lu_udiag, lu_bias, lu_perm,
        z,
        fW1f, fW2f, mW1f, mW2f, fWoutf, mWoutf, minf, cfrag, cpb,
        encW1f, encW2f, epb,
        weffF, mlutF, beff, idk, luc);

    ctx_mfma<<<dim3(576, 3), B, 0, stream>>>(cfrag, cpb, encW1f, encW2f, epb,
                                             ctxoutf, ehw);

    mega_all<<<1152, B, 0, stream>>>(z, ctxoutf, weffF, mlutF, beff, minf,
                                     fW1f, fW2f, mW1f, mW2f, fWoutf, mWoutf,
                                     sp_bb1, sp_bb2, made_bb1, made_bb2,
                                     sp_bout, made_bout,
                                     lu_bias, idk, luc, ehw, out);
}

// Round 23
// 233.653 us; speedup vs baseline: 1.0110x; 1.0110x over previous
//
#include <hip/hip_runtime.h>
#include <math.h>

#define NHW   9216     // 96*96
#define NROWS 36864    // NHW*4

typedef _Float16 f16;
typedef _Float16 f16x8 __attribute__((ext_vector_type(8)));
typedef float    f32x4 __attribute__((ext_vector_type(4)));

// fast transcendentals (hardware v_exp_f32 / v_log_f32; rel err ~1e-5, fine vs thr 10.3)
__device__ __forceinline__ float fexpf(float x) { return __expf(x); }
__device__ __forceinline__ float flogf(float x) { return __logf(x); }

__device__ __forceinline__ float softplusf(float x) {
    return fmaxf(x, 0.f) + log1pf(fexpf(-fabsf(x)));
}

// LDS-only barrier: global loads into private VGPRs stay in flight across it.
__device__ __forceinline__ void barrier_lgkm() {
    __builtin_amdgcn_sched_barrier(0);
    asm volatile("s_waitcnt lgkmcnt(0)" ::: "memory");
    __builtin_amdgcn_s_barrier();
    __builtin_amdgcn_sched_barrier(0);
}

// ---------------- knots helper ----------------
__device__ __forceinline__ void knots8(const float* __restrict__ u, float* c, float* w) {
    float mx = u[0];
    #pragma unroll
    for (int k = 1; k < 8; ++k) mx = fmaxf(mx, u[k]);
    float e[8]; float s = 0.f;
    #pragma unroll
    for (int k = 0; k < 8; ++k) { e[k] = fexpf(u[k] - mx); s += e[k]; }
    float inv = 1.f / s;
    c[0] = -3.f;
    float cum = 0.f;
    #pragma unroll
    for (int k = 0; k < 8; ++k) {
        float v = 0.001f + 0.992f * e[k] * inv;
        cum += v;
        c[k + 1] = cum * 6.f - 3.f;
    }
    c[8] = 3.f;
    #pragma unroll
    for (int k = 0; k < 8; ++k) w[k] = c[k + 1] - c[k];
}

// ---------------- merged setup kernel: snorm | pack | prep ----------------
// blocks [0,2304): snorm tiles; [2304,5049): pack (flat 702496 elems);
// [5049,5123): prep fragment work (each recomputes Mlu in LDS); block 5123: idk+luc.
__global__ __launch_bounds__(256) void setup_kernel(
    const float* __restrict__ x,
    const float* __restrict__ sp_bW1, const float* __restrict__ sp_bW2,
    const float* __restrict__ made_bW1, const float* __restrict__ made_bW2,
    const float* __restrict__ sp_Wout, const float* __restrict__ made_Wout,
    const float* __restrict__ sp_Win, const float* __restrict__ made_W0,
    const float* __restrict__ sp_bCW, const float* __restrict__ made_ctxW,
    const float* __restrict__ made_bCW,
    const float* __restrict__ sp_bin, const float* __restrict__ sp_bCb,
    const float* __restrict__ made_ctxb, const float* __restrict__ made_b0,
    const float* __restrict__ made_bCb,
    const float* __restrict__ enc_W1, const float* __restrict__ enc_b1,
    const float* __restrict__ enc_W2, const float* __restrict__ enc_b2,
    const float* __restrict__ sp_uw, const float* __restrict__ sp_uh,
    const float* __restrict__ sp_ud,
    const float* __restrict__ lu_lower, const float* __restrict__ lu_upper,
    const float* __restrict__ lu_udiag, const float* __restrict__ lu_bias,
    const int*   __restrict__ lu_perm,
    float* __restrict__ z,
    f16* __restrict__ fW1f, f16* __restrict__ fW2f,
    f16* __restrict__ mW1f, f16* __restrict__ mW2f,
    f16* __restrict__ fWoutf, f16* __restrict__ mWoutf,
    f16* __restrict__ minf,
    f16* __restrict__ cfrag, float* __restrict__ cpb,
    f16* __restrict__ encW1f, f16* __restrict__ encW2f, float* __restrict__ epb,
    f16* __restrict__ weffF, f16* __restrict__ mlutF,
    float* __restrict__ beff, float* __restrict__ idk, float* __restrict__ luc)
{
    __shared__ float sS[33][34];
    __shared__ float sMlu[4][16][16];
    const int bid = blockIdx.x;
    const int t = threadIdx.x;

    if (bid < 2304) {
        const int bs   = bid / 36;
        const int tile = bid % 36;
        const int ti = tile / 6, tj = tile % 6;
        const int i0 = ti * 16, j0 = tj * 16;
        const int b = bs >> 4, s = bs & 15;
        const float* xb = x + (size_t)(bs * 3) * 36864;
        for (int e = t; e < 33 * 33; e += 256) {
            int row = e / 33, col = e % 33;
            int hh = 2 * i0 - 1 + row, ww = 2 * j0 - 1 + col;
            float acc = 0.f;
            if (hh >= 0 && hh < 192 && ww >= 0 && ww < 192) {
                #pragma unroll
                for (int c = 0; c < 3; ++c) {
                    float v = xb[c * 36864 + hh * 192 + ww];
                    acc += v * v;
                }
            }
            sS[row][col] = acc;
        }
        __syncthreads();
        const int oi = t >> 4, oj = t & 15;
        float sum = 0.f;
        #pragma unroll
        for (int dr = 0; dr < 3; ++dr)
            #pragma unroll
            for (int dc = 0; dc < 3; ++dc)
                sum += sS[2 * oi + dr][2 * oj + dc];
        const int i = i0 + oi, j = j0 + oj;
        z[((size_t)(i * 96 + j) * 4 + b) * 16 + s] = sqrtf(sum);
        return;
    }

    if (bid < 5049) {
        int idx = (bid - 2304) * 256 + t;
        if (idx < 131072) {
            int e = idx;
            int mtx = e >> 14, f = e & 16383;
            int nt = f >> 11, ks = (f >> 9) & 3, l = (f >> 3) & 63, j = f & 7;
            int n = nt * 16 + (l & 15), k = ks * 32 + ((l >> 4) & 3) * 8 + j;
            fW1f[e] = (f16)sp_bW1[mtx * 16384 + n * 128 + k];
            return;
        }
        idx -= 131072;
        if (idx < 131072) {
            int e = idx;
            int mtx = e >> 14, f = e & 16383;
            int nt = f >> 11, ks = (f >> 9) & 3, l = (f >> 3) & 63, j = f & 7;
            int n = nt * 16 + (l & 15), k = ks * 32 + ((l >> 4) & 3) * 8 + j;
            fW2f[e] = (f16)sp_bW2[mtx * 16384 + n * 128 + k];
            return;
        }
        idx -= 131072;
        if (idx < 32768) {
            int e = idx;
            int mtx = e >> 14, f = e & 16383;
            int nt = f >> 11, ks = (f >> 9) & 3, l = (f >> 3) & 63, j = f & 7;
            int n = nt * 16 + (l & 15), k = ks * 32 + ((l >> 4) & 3) * 8 + j;
            mW1f[e] = ((n % 15) >= (k % 15)) ? (f16)made_bW1[mtx * 16384 + n * 128 + k] : (f16)0.f;
            return;
        }
        idx -= 32768;
        if (idx < 32768) {
            int e = idx;
            int mtx = e >> 14, f = e & 16383;
            int nt = f >> 11, ks = (f >> 9) & 3, l = (f >> 3) & 63, j = f & 7;
            int n = nt * 16 + (l & 15), k = ks * 32 + ((l >> 4) & 3) * 8 + j;
            mW2f[e] = ((n % 15) >= (k % 15)) ? (f16)made_bW2[mtx * 16384 + n * 128 + k] : (f16)0.f;
            return;
        }
        idx -= 32768;
        if (idx < 98304) {
            int e = idx;
            int s = e / 24576, f = e % 24576;
            int nt = f >> 11, ks = (f >> 9) & 3, l = (f >> 3) & 63, j = f & 7;
            int n = nt * 16 + (l & 15), k = ks * 32 + ((l >> 4) & 3) * 8 + j;
            fWoutf[e] = (n < 184) ? (f16)sp_Wout[s * 23552 + n * 128 + k] : (f16)0.f;
            return;
        }
        idx -= 98304;
        if (idx < 4096) {
            int f = idx;
            int nt = f >> 11, ks = (f >> 9) & 3, l = (f >> 3) & 63, j = f & 7;
            int n = nt * 16 + (l & 15), k = ks * 32 + ((l >> 4) & 3) * 8 + j;
            mWoutf[idx] = (((n & 15) > (k % 15)) && n < 32) ? (f16)made_Wout[n * 128 + k] : (f16)0.f;
            return;
        }
        idx -= 4096;
        if (idx < 4096) {
            int f = idx;
            int nt = f >> 9, l = (f >> 3) & 63, j = f & 7;
            int n = nt * 16 + (l & 15), k = ((l >> 4) & 3) * 8 + j;
            minf[idx] = (k < 16 && (n % 15) >= k) ? (f16)made_W0[n * 16 + k] : (f16)0.f;
            return;
        }
        idx -= 4096;
        if (idx < 245760) {
            int e = idx;
            int s = e / 49152, f = e % 49152;
            int nt = f >> 11, ks = (f >> 9) & 3, l = (f >> 3) & 63, j = f & 7;
            int n = nt * 16 + (l & 15), k = ks * 32 + ((l >> 4) & 3) * 8 + j;
            float v;
            if (s < 4) {
                if (n < 128)      v = sp_Win[s * 17408 + n * 136 + 8 + k];
                else if (n < 256) v = sp_bCW[(size_t)(s * 2 + 0) * 16384 + (n - 128) * 128 + k];
                else              v = sp_bCW[(size_t)(s * 2 + 1) * 16384 + (n - 256) * 128 + k];
            } else {
                if (n < 128)      v = made_ctxW[n * 128 + k];
                else if (n < 256) v = made_bCW[(n - 128) * 128 + k];
                else              v = made_bCW[16384 + (n - 256) * 128 + k];
            }
            cfrag[e] = (f16)v;
            return;
        }
        idx -= 245760;
        if (idx < 1920) {
            int e = idx;
            int s = e / 384, n = e % 384;
            float v;
            if (s < 4) {
                if (n < 128)      v = sp_bin[s * 128 + n];
                else if (n < 256) v = sp_bCb[(s * 2 + 0) * 128 + (n - 128)];
                else              v = sp_bCb[(s * 2 + 1) * 128 + (n - 256)];
            } else {
                if (n < 128)      v = made_ctxb[n] + made_b0[n];
                else if (n < 256) v = made_bCb[n - 128];
                else              v = made_bCb[128 + (n - 256)];
            }
            cpb[e] = v;
            return;
        }
        idx -= 1920;
        if (idx < 16384) {
            int f = idx;
            int nt = f >> 11, ks = (f >> 9) & 3, l = (f >> 3) & 63, j = f & 7;
            int n = nt * 16 + (l & 15), k = ks * 32 + ((l >> 4) & 3) * 8 + j;
            encW1f[idx] = (f16)enc_W1[n * 128 + k];
            return;
        }
        idx -= 16384;
        if (idx < 4096) {
            int f = idx;
            int nt = f >> 11, ks = (f >> 9) & 3, l = (f >> 3) & 63, j = f & 7;
            int n = nt * 16 + (l & 15), k = ks * 32 + ((l >> 4) & 3) * 8 + j;
            encW2f[idx] = (n < 32) ? (f16)enc_W2[n * 128 + k] : (f16)0.f;
            return;
        }
        idx -= 4096;
        if (idx < 160) {
            epb[idx] = (idx < 128) ? enc_b1[idx] : enc_b2[idx - 128];
        }
        return;
    }

    if (bid == 5123) {
        if (t < 32) {
            int s = t >> 3, dim = t & 7;
            float* o = idk + (s * 8 + dim) * 48;
            float c[9], w[8];
            knots8(sp_uw + s * 64 + dim * 8, c, w);
            #pragma unroll
            for (int k = 0; k < 9; ++k) o[k] = c[k];
            #pragma unroll
            for (int k = 0; k < 8; ++k) o[9 + k] = w[k];
            knots8(sp_uh + s * 64 + dim * 8, c, w);
            #pragma unroll
            for (int k = 0; k < 9; ++k) o[17 + k] = c[k];
            #pragma unroll
            for (int k = 0; k < 8; ++k) o[26 + k] = w[k];
            o[34] = 1.f; o[42] = 1.f;
            #pragma unroll
            for (int k = 0; k < 7; ++k) o[35 + k] = 0.001f + softplusf(sp_ud[s * 56 + dim * 7 + k]);
        } else if (t == 32) {
            float c0 = 0.f;
            for (int k = 0; k < 64; ++k)
                c0 += flogf(softplusf(lu_udiag[k]) + 0.001f);
            luc[0] = c0;
        }
        return;
    }

    // ---- prep fragment blocks [5049,5123) ----
    {
        if (t < 64) {
            int s = t >> 4, d = t & 15;
            const float* L  = lu_lower + s * 256;
            const float* U  = lu_upper + s * 256;
            const float* ud = lu_udiag + s * 16;
            const int*   pm = lu_perm + s * 16;
            for (int c = 0; c < 16; ++c) {
                float m = 0.f;
                if (c > d)       m += U[d * 16 + c];
                else if (c == d) m += softplusf(ud[d]) + 0.001f;
                for (int e = 0; e < d && e <= c; ++e) {
                    float u = (c > e) ? U[e * 16 + c] : (softplusf(ud[e]) + 0.001f);
                    m += L[d * 16 + e] * u;
                }
                sMlu[s][d][pm[c]] = m;
            }
        }
        __syncthreads();
        int idx = (bid - 5049) * 256 + t;
        if (idx < 16384) {
            int e = idx;
            int s = e >> 12, f = e & 4095;
            int nt = f >> 9, l = (f >> 3) & 63, j = f & 7;
            int n = nt * 16 + (l & 15), k = ((l >> 4) & 3) * 8 + j;
            float v = 0.f;
            if (k < 16) {
                #pragma unroll
                for (int p = 0; p < 8; ++p)
                    v += sMlu[s][2 * p][k] * sp_Win[s * 17408 + n * 136 + p];
            }
            weffF[e] = (f16)v;
        } else if (idx < 18432) {
            int e = idx - 16384;
            int s = e >> 9, f = e & 511;
            int l = f >> 3, j = f & 7;
            int n = l & 15, k = (l >> 4) * 8 + j;
            mlutF[e] = (k < 16) ? (f16)sMlu[s][n][k] : (f16)0.f;
        } else if (idx < 18944) {
            int e = idx - 18432;
            int s = e >> 7, n = e & 127;
            float v = 0.f;
            #pragma unroll
            for (int p = 0; p < 8; ++p)
                v += lu_bias[s * 16 + 2 * p] * sp_Win[s * 17408 + n * 136 + p];
            beff[e] = v;
        }
        return;
    }
}

// ---------------- ctx-chain MFMA: 2 slices per block ----------------
__global__ __launch_bounds__(256) void ctx_mfma(
    const f16* __restrict__ cfrag,
    const float* __restrict__ cpb,
    const f16* __restrict__ encW1f, const f16* __restrict__ encW2f,
    const float* __restrict__ epb,
    f16* __restrict__ ctxoutf, float* __restrict__ ehw)
{
    __shared__ alignas(16) f16 cS[16][136];
    __shared__ alignas(16) f16 hS[16][136];
    const int tid = threadIdx.x, w = tid >> 6, l = tid & 63;
    const int m0 = blockIdx.x * 16;
    const int sy = blockIdx.y;
    const int lr = l & 15, lq = l >> 4;
    #pragma unroll
    for (int it = 0; it < 2; ++it) {
        int e = tid + it * 256;
        int r = e >> 5, c4 = (e & 31) * 4;
        int hw = m0 + r;
        int ii = hw / 96, jj = hw % 96;
        #pragma unroll
        for (int q = 0; q < 4; ++q) {
            int c = c4 + q;
            int pos = (c < 64) ? ii : jj;
            int cc = c & 63;
            int k = cc >> 1;
            float invf = exp2f((float)k * -0.4152410118609203f);  // 10000^(-k/32)
            float v = (float)pos * invf;
            cS[r][c] = (f16)((cc & 1) ? cosf(v) : sinf(v));
        }
    }
    __syncthreads();
    const f32x4 vzero = {0.f, 0.f, 0.f, 0.f};
    #pragma unroll
    for (int sub = 0; sub < 2; ++sub) {
        const int s = sy * 2 + sub;
        if (s < 5) {
            f32x4 acc[6];
            #pragma unroll
            for (int q = 0; q < 6; ++q) acc[q] = vzero;
            const f16* wb = cfrag + (size_t)s * 49152;
            #pragma unroll
            for (int ks = 0; ks < 4; ++ks) {
                f16x8 a = *(const f16x8*)&cS[lr][ks * 32 + lq * 8];
                #pragma unroll
                for (int q = 0; q < 6; ++q) {
                    int g = w * 6 + q;
                    f16x8 b = *(const f16x8*)(wb + (size_t)((g * 4 + ks) * 64 + l) * 8);
                    acc[q] = __builtin_amdgcn_mfma_f32_16x16x32_f16(a, b, acc[q], 0, 0, 0);
                }
            }
            #pragma unroll
            for (int q = 0; q < 6; ++q) {
                int g = w * 6 + q, n = g * 16 + lr;
                float bias = cpb[s * 384 + n];
                #pragma unroll
                for (int r = 0; r < 4; ++r) {
                    float val = acc[q][r] + bias;
                    if (n >= 128) val = 1.f / (1.f + fexpf(-val));
                    ctxoutf[(size_t)s * NHW * 384 + (size_t)(m0 + lq * 4 + r) * 384 + n] = (f16)val;
                }
            }
        } else {
            f32x4 acc0 = vzero, acc1 = vzero;
            #pragma unroll
            for (int ks = 0; ks < 4; ++ks) {
                f16x8 a = *(const f16x8*)&cS[lr][ks * 32 + lq * 8];
                f16x8 b0 = *(const f16x8*)(encW1f + (((w * 2 + 0) * 4 + ks) * 64 + l) * 8);
                f16x8 b1 = *(const f16x8*)(encW1f + (((w * 2 + 1) * 4 + ks) * 64 + l) * 8);
                acc0 = __builtin_amdgcn_mfma_f32_16x16x32_f16(a, b0, acc0, 0, 0, 0);
                acc1 = __builtin_amdgcn_mfma_f32_16x16x32_f16(a, b1, acc1, 0, 0, 0);
            }
            {
                int n0 = (w * 2 + 0) * 16 + lr, n1 = (w * 2 + 1) * 16 + lr;
                float bi0 = epb[n0], bi1 = epb[n1];
                #pragma unroll
                for (int r = 0; r < 4; ++r) {
                    float v0 = acc0[r] + bi0, v1 = acc1[r] + bi1;
                    hS[lq * 4 + r][n0] = (f16)(v0 / (1.f + fexpf(-v0)));
                    hS[lq * 4 + r][n1] = (f16)(v1 / (1.f + fexpf(-v1)));
                }
            }
            __syncthreads();
            if (w < 2) {
                f32x4 po = vzero;
                #pragma unroll
                for (int ks = 0; ks < 4; ++ks) {
                    f16x8 a = *(const f16x8*)&hS[lr][ks * 32 + lq * 8];
                    f16x8 b = *(const f16x8*)(encW2f + ((w * 4 + ks) * 64 + l) * 8);
                    po = __builtin_amdgcn_mfma_f32_16x16x32_f16(a, b, po, 0, 0, 0);
                }
                int n = w * 16 + lr;
                float bias = epb[128 + n];
                #pragma unroll
                for (int r = 0; r < 4; ++r)
                    ehw[(size_t)(m0 + lq * 4 + r) * 32 + n] = po[r] + bias;
            }
        }
    }
}

// ---------------- rational-quadratic spline ----------------
__device__ __forceinline__ void rqs_core(float x, const float* cw, const float* wd,
                                         const float* ch, const float* hg, const float* dd,
                                         float& y, float& ld) {
    bool inside = (x >= -3.f) && (x <= 3.f);
    float xc = fminf(fmaxf(x, -3.f), 3.f);
    float cwk = cw[0], wk = wd[0], chk = ch[0], hk = hg[0], d0 = dd[0], d1 = dd[1];
    #pragma unroll
    for (int k = 1; k < 8; ++k) {
        if (xc >= cw[k]) { cwk = cw[k]; wk = wd[k]; chk = ch[k]; hk = hg[k]; d0 = dd[k]; d1 = dd[k + 1]; }
    }
    float dl = hk / wk;
    float th = (xc - cwk) / wk;
    float t1 = th * (1.f - th);
    float den = dl + (d0 + d1 - 2.f * dl) * t1;
    float yy = chk + hk * (dl * th * th + d0 * t1) / den;
    float om = 1.f - th;
    float dnum = dl * dl * (d1 * th * th + 2.f * dl * t1 + d0 * om * om);
    float lld = flogf(dnum) - 2.f * flogf(den);
    y  = inside ? yy : x;
    ld = inside ? lld : 0.f;
}

__device__ __forceinline__ void rqs1(float x,
                                     const float* __restrict__ uw,
                                     const float* __restrict__ uh,
                                     const float* __restrict__ ud,
                                     float& y, float& ld) {
    float cw[9], wd[8], ch[9], hg[8], dd[9];
    knots8(uw, cw, wd);
    knots8(uh, ch, hg);
    dd[0] = 1.f; dd[8] = 1.f;
    #pragma unroll
    for (int k = 0; k < 7; ++k) dd[k + 1] = 0.001f + softplusf(ud[k]);
    rqs_core(x, cw, wd, ch, hg, dd, y, ld);
}

__device__ __forceinline__ void rqs1_pre(float x, const float* __restrict__ kn,
                                         float& y, float& ld) {
    float cw[9], wd[8], ch[9], hg[8], dd[9];
    #pragma unroll
    for (int k = 0; k < 9; ++k) cw[k] = kn[k];
    #pragma unroll
    for (int k = 0; k < 8; ++k) wd[k] = kn[9 + k];
    #pragma unroll
    for (int k = 0; k < 9; ++k) ch[k] = kn[17 + k];
    #pragma unroll
    for (int k = 0; k < 8; ++k) hg[k] = kn[26 + k];
    #pragma unroll
    for (int k = 0; k < 9; ++k) dd[k] = kn[34 + k];
    rqs_core(x, cw, wd, ch, hg, dd, y, ld);
}

// ---------------- prefetch helpers ----------------
__device__ __forceinline__ void load8(const f16* __restrict__ w, int nt0, int l,
                                      f16x8 B[8]) {
    #pragma unroll
    for (int q = 0; q < 2; ++q)
        #pragma unroll
        for (int ks = 0; ks < 4; ++ks)
            B[q * 4 + ks] = *(const f16x8*)(w + (nt0 + q) * 2048 + ks * 512 + l * 8);
}

// two-tile GEMM: shared B-frags, A-frags from both tiles' LDS (stride-templated)
template<int S>
__device__ __forceinline__ void gemm16(const f16 (*__restrict__ SA)[S],
                                       const f16 (*__restrict__ SB)[S],
                                       int lr, int lqw, const f16x8 B[8],
                                       f32x4& aA0, f32x4& aA1, f32x4& aB0, f32x4& aB1) {
    __builtin_amdgcn_s_setprio(1);
    #pragma unroll
    for (int ks = 0; ks < 4; ++ks) {
        f16x8 aA = *(const f16x8*)&SA[lr][ks * 32 + lqw * 8];
        f16x8 aB = *(const f16x8*)&SB[lr][ks * 32 + lqw * 8];
        aA0 = __builtin_amdgcn_mfma_f32_16x16x32_f16(aA, B[ks], aA0, 0, 0, 0);
        aB0 = __builtin_amdgcn_mfma_f32_16x16x32_f16(aB, B[ks], aB0, 0, 0, 0);
        aA1 = __builtin_amdgcn_mfma_f32_16x16x32_f16(aA, B[4 + ks], aA1, 0, 0, 0);
        aB1 = __builtin_amdgcn_mfma_f32_16x16x32_f16(aB, B[4 + ks], aB1, 0, 0, 0);
    }
    __builtin_amdgcn_s_setprio(0);
}

// ---------------- merged pipeline: TWO 16-row tiles per block ----------------
// LDS union kept (uS/pS never live together); plain launch_bounds — the r22
// (256,5) experiment forced VGPR 104->48 and spilled 570 MB to scratch.
__global__ __launch_bounds__(256) void mega_all(
    const float* __restrict__ zg,
    const f16*  __restrict__ ctxoutf,   // [5][9216][384]
    const f16*  __restrict__ weffF,     // [4][4096]
    const f16*  __restrict__ mlutF,     // [4][512]
    const float* __restrict__ beffv,    // [4][128]
    const f16*  __restrict__ minf,      // [4096]
    const f16*  __restrict__ fW1f,      // [4][2][16384]
    const f16*  __restrict__ fW2f,
    const f16*  __restrict__ mW1f,      // [2][16384]
    const f16*  __restrict__ mW2f,
    const f16*  __restrict__ fWoutf,    // [4][24576]
    const f16*  __restrict__ mWoutf,    // [4096]
    const float* __restrict__ sp_bb1,   // [4][2][128]
    const float* __restrict__ sp_bb2,
    const float* __restrict__ made_bb1, // [2][128]
    const float* __restrict__ made_bb2,
    const float* __restrict__ sp_bout,  // [4][184]
    const float* __restrict__ made_bout,// [32]
    const float* __restrict__ lu_bias,  // [4][16]
    const float* __restrict__ idk,      // [4][8][48]
    const float* __restrict__ luc,      // [1]
    const float* __restrict__ ehw,      // [9216][32]
    float* __restrict__ out)            // [4][9216]
{
    __shared__ alignas(16) f16 tS[2][16][136];
    __shared__ alignas(16) f16 uS[2][16][196];   // union: residual hidden (cols<128) / WOUT out (cols<196)
    __shared__ alignas(16) f16 zS[2][16][32];
    __shared__ float zlu[2][16][17];
    __shared__ float zO[2][16][17];
    __shared__ float ldS[2][16][17];
    const int tid = threadIdx.x;
    const int w   = tid >> 6;
    const int l   = tid & 63;
    const int lr  = l & 15;
    const int lqw = l >> 4;
    const int m0  = blockIdx.x * 32;
    const int hwA = (m0 >> 2) + lqw;
    const int hwB = hwA + 4;
    const int nt0 = w * 2;
    const f32x4 vzero = {0.f, 0.f, 0.f, 0.f};

    #pragma unroll
    for (int it = 0; it < 2; ++it) {
        int e = tid + it * 256;
        int rr = e >> 4, d2 = e & 15;
        int t2 = rr >> 4, r2 = rr & 15;
        zS[t2][r2][d2] = (f16)zg[(size_t)(m0 + rr) * 16 + d2];
        zS[t2][r2][16 + d2] = (f16)0.f;
    }
    float luc0 = luc[0];
    float ldA = 0.f, ldB = 0.f;

    f16x8 B[8];
    f16x8 bml;
    B[0] = *(const f16x8*)(weffF + 3 * 4096 + ((nt0 + 0) * 64 + l) * 8);
    B[1] = *(const f16x8*)(weffF + 3 * 4096 + ((nt0 + 1) * 64 + l) * 8);
    bml  = *(const f16x8*)(mlutF + 3 * 512 + l * 8);
    barrier_lgkm();

    const int n0q = (w + 0) * 16 + lr, n1q = (w + 4) * 16 + lr, n2q = (w + 8) * 16 + lr;

    float tRA[2][4], tRB[2][4];

    for (int i = 3; i >= 0; --i) {
        const f16* cbA = ctxoutf + (size_t)i * NHW * 384 + (size_t)hwA * 384;
        const f16* cbB = ctxoutf + (size_t)i * NHW * 384 + (size_t)hwB * 384;
        // ---- IN ----
        {
            f16x8 aA = *(const f16x8*)&zS[0][lr][lqw * 8];
            f16x8 aB = *(const f16x8*)&zS[1][lr][lqw * 8];
            if (w < 2) {
                float bl = lu_bias[i * 16 + lr];
                f32x4 c = {bl, bl, bl, bl};
                c = __builtin_amdgcn_mfma_f32_16x16x32_f16(w == 0 ? aA : aB, bml, c, 0, 0, 0);
                #pragma unroll
                for (int r = 0; r < 4; ++r)
                    zlu[w][lqw * 4 + r][lr] = c[r];
            }
            #pragma unroll
            for (int t = 0; t < 2; ++t) {
                int n = (nt0 + t) * 16 + lr;
                float bf = beffv[i * 128 + n];
                float ciA = (float)cbA[n] + bf;
                float ciB = (float)cbB[n] + bf;
                f32x4 cA = {ciA, ciA, ciA, ciA};
                f32x4 cB = {ciB, ciB, ciB, ciB};
                cA = __builtin_amdgcn_mfma_f32_16x16x32_f16(aA, B[t], cA, 0, 0, 0);
                cB = __builtin_amdgcn_mfma_f32_16x16x32_f16(aB, B[t], cB, 0, 0, 0);
                #pragma unroll
                for (int r = 0; r < 4; ++r) {
                    tRA[t][r] = cA[r];
                    tRB[t][r] = cB[r];
                    tS[0][lqw * 4 + r][n] = (f16)fmaxf(cA[r], 0.f);
                    tS[1][lqw * 4 + r][n] = (f16)fmaxf(cB[r], 0.f);
                }
            }
            load8(fW1f + (size_t)i * 32768, nt0, l, B);
        }
        barrier_lgkm();
        // ---- residual blocks ----
        #pragma unroll
        for (int blk = 0; blk < 2; ++blk) {
            // W1
            {
                f32x4 aA0 = vzero, aA1 = vzero, aB0 = vzero, aB1 = vzero;
                gemm16<136>(tS[0], tS[1], lr, lqw, B, aA0, aA1, aB0, aB1);
                load8(fW2f + (size_t)i * 32768 + blk * 16384, nt0, l, B);
                const float* bb1p = sp_bb1 + i * 256 + blk * 128;
                float bi0 = bb1p[(nt0 + 0) * 16 + lr];
                float bi1 = bb1p[(nt0 + 1) * 16 + lr];
                #pragma unroll
                for (int r = 0; r < 4; ++r) {
                    uS[0][lqw * 4 + r][(nt0 + 0) * 16 + lr] = (f16)fmaxf(aA0[r] + bi0, 0.f);
                    uS[0][lqw * 4 + r][(nt0 + 1) * 16 + lr] = (f16)fmaxf(aA1[r] + bi1, 0.f);
                    uS[1][lqw * 4 + r][(nt0 + 0) * 16 + lr] = (f16)fmaxf(aB0[r] + bi0, 0.f);
                    uS[1][lqw * 4 + r][(nt0 + 1) * 16 + lr] = (f16)fmaxf(aB1[r] + bi1, 0.f);
                }
            }
            barrier_lgkm();
            // W2
            {
                f32x4 aA0 = vzero, aA1 = vzero, aB0 = vzero, aB1 = vzero;
                gemm16<196>(uS[0], uS[1], lr, lqw, B, aA0, aA1, aB0, aB1);
                if (blk == 0) load8(fW1f + (size_t)i * 32768 + 16384, nt0, l, B);
                else {
                    const f16* wo = fWoutf + (size_t)i * 24576;
                    #pragma unroll
                    for (int t2 = 0; t2 < 2; ++t2)
                        #pragma unroll
                        for (int ks = 0; ks < 4; ++ks)
                            B[t2 * 4 + ks] = *(const f16x8*)(wo + (w + t2 * 4) * 2048 + ks * 512 + l * 8);
                }
                const float* bb2p = sp_bb2 + i * 256 + blk * 128;
                float bi0 = bb2p[(nt0 + 0) * 16 + lr];
                float bi1 = bb2p[(nt0 + 1) * 16 + lr];
                float gA0 = (float)cbA[128 + blk * 128 + (nt0 + 0) * 16 + lr];
                float gA1 = (float)cbA[128 + blk * 128 + (nt0 + 1) * 16 + lr];
                float gB0 = (float)cbB[128 + blk * 128 + (nt0 + 0) * 16 + lr];
                float gB1 = (float)cbB[128 + blk * 128 + (nt0 + 1) * 16 + lr];
                #pragma unroll
                for (int r = 0; r < 4; ++r) {
                    tRA[0][r] += (aA0[r] + bi0) * gA0;
                    tRA[1][r] += (aA1[r] + bi1) * gA1;
                    tRB[0][r] += (aB0[r] + bi0) * gB0;
                    tRB[1][r] += (aB1[r] + bi1) * gB1;
                    if (blk == 0) {
                        tS[0][lqw * 4 + r][(nt0 + 0) * 16 + lr] = (f16)fmaxf(tRA[0][r], 0.f);
                        tS[0][lqw * 4 + r][(nt0 + 1) * 16 + lr] = (f16)fmaxf(tRA[1][r], 0.f);
                        tS[1][lqw * 4 + r][(nt0 + 0) * 16 + lr] = (f16)fmaxf(tRB[0][r], 0.f);
                        tS[1][lqw * 4 + r][(nt0 + 1) * 16 + lr] = (f16)fmaxf(tRB[1][r], 0.f);
                    } else {
                        tS[0][lqw * 4 + r][(nt0 + 0) * 16 + lr] = (f16)tRA[0][r];
                        tS[0][lqw * 4 + r][(nt0 + 1) * 16 + lr] = (f16)tRA[1][r];
                        tS[1][lqw * 4 + r][(nt0 + 0) * 16 + lr] = (f16)tRB[0][r];
                        tS[1][lqw * 4 + r][(nt0 + 1) * 16 + lr] = (f16)tRB[1][r];
                    }
                }
            }
            barrier_lgkm();
        }
        // ---- WOUT -> uS (union; both tiles; B holds nt w, w+4) ----
        {
            f32x4 pA0 = vzero, pA1 = vzero, pA2 = vzero;
            f32x4 pB0 = vzero, pB1 = vzero, pB2 = vzero;
            const f16* wo = fWoutf + (size_t)i * 24576;
            __builtin_amdgcn_s_setprio(1);
            #pragma unroll
            for (int ks = 0; ks < 4; ++ks) {
                f16x8 aA = *(const f16x8*)&tS[0][lr][ks * 32 + lqw * 8];
                f16x8 aB = *(const f16x8*)&tS[1][lr][ks * 32 + lqw * 8];
                pA0 = __builtin_amdgcn_mfma_f32_16x16x32_f16(aA, B[ks], pA0, 0, 0, 0);
                pB0 = __builtin_amdgcn_mfma_f32_16x16x32_f16(aB, B[ks], pB0, 0, 0, 0);
                pA1 = __builtin_amdgcn_mfma_f32_16x16x32_f16(aA, B[4 + ks], pA1, 0, 0, 0);
                pB1 = __builtin_amdgcn_mfma_f32_16x16x32_f16(aB, B[4 + ks], pB1, 0, 0, 0);
                f16x8 b2 = *(const f16x8*)(wo + (w + 8) * 2048 + ks * 512 + l * 8);
                pA2 = __builtin_amdgcn_mfma_f32_16x16x32_f16(aA, b2, pA2, 0, 0, 0);
                pB2 = __builtin_amdgcn_mfma_f32_16x16x32_f16(aB, b2, pB2, 0, 0, 0);
            }
            __builtin_amdgcn_s_setprio(0);
            if (i > 0) {
                B[0] = *(const f16x8*)(weffF + (i - 1) * 4096 + ((nt0 + 0) * 64 + l) * 8);
                B[1] = *(const f16x8*)(weffF + (i - 1) * 4096 + ((nt0 + 1) * 64 + l) * 8);
                bml  = *(const f16x8*)(mlutF + (i - 1) * 512 + l * 8);
            } else {
                B[0] = *(const f16x8*)(minf + ((nt0 + 0) * 64 + l) * 8);
                B[1] = *(const f16x8*)(minf + ((nt0 + 1) * 64 + l) * 8);
            }
            const float* bo = sp_bout + i * 184;
            float b0v = bo[n0q], b1v = bo[n1q];
            float b2v = (n2q < 184) ? bo[n2q] : 0.f;
            #pragma unroll
            for (int r = 0; r < 4; ++r) {
                uS[0][lqw * 4 + r][n0q] = (f16)(pA0[r] + b0v);
                uS[1][lqw * 4 + r][n0q] = (f16)(pB0[r] + b0v);
                uS[0][lqw * 4 + r][n1q] = (f16)(pA1[r] + b1v);
                uS[1][lqw * 4 + r][n1q] = (f16)(pB1[r] + b1v);
                if (n2q < 184) {
                    uS[0][lqw * 4 + r][n2q] = (f16)(pA2[r] + b2v);
                    uS[1][lqw * 4 + r][n2q] = (f16)(pB2[r] + b2v);
                }
            }
        }
        barrier_lgkm();
        // ---- SPLINE (load-balanced: each 16-thread group does 1 tr + 1 id) ----
        {
            const int g = tid >> 4, rw = tid & 15;
            const int dim = (g < 8) ? g : (g - 8);
            const int trT = (g < 8) ? 0 : 1;   // tile for tr
            const int idT = 1 - trT;           // tile for id
            float y, ldv;
            {
                const float is = 0.08838834764831845f;
                float uw[8], uh[8], udv[7];
                const f16* pr = &uS[trT][rw][dim * 23];
                #pragma unroll
                for (int k = 0; k < 8; ++k) { uw[k] = (float)pr[k] * is; uh[k] = (float)pr[8 + k] * is; }
                #pragma unroll
                for (int k = 0; k < 7; ++k) udv[k] = (float)pr[16 + k];
                float xx = zlu[trT][rw][2 * dim + 1];
                rqs1(xx, uw, uh, udv, y, ldv);
                zO[trT][rw][2 * dim + 1] = y;
                zS[trT][rw][2 * dim + 1] = (f16)y;
                if (trT == 0) ldA += ldv; else ldB += ldv;
            }
            {
                float xx = zlu[idT][rw][2 * dim];
                rqs1_pre(xx, idk + i * 384 + dim * 48, y, ldv);
                zO[idT][rw][2 * dim] = y;
                zS[idT][rw][2 * dim] = (f16)y;
                if (idT == 0) ldA += ldv; else ldB += ldv;
            }
        }
        barrier_lgkm();
    }

    // publish logq partials
    ldS[0][tid >> 4][tid & 15] = ldA;
    ldS[1][tid >> 4][tid & 15] = ldB;

    // ---- MADE stage ----
    {
        const f16* cbA = ctxoutf + (size_t)4 * NHW * 384 + (size_t)hwA * 384;
        const f16* cbB = ctxoutf + (size_t)4 * NHW * 384 + (size_t)hwB * 384;
        {
            f16x8 aA = *(const f16x8*)&zS[0][lr][lqw * 8];
            f16x8 aB = *(const f16x8*)&zS[1][lr][lqw * 8];
            #pragma unroll
            for (int t = 0; t < 2; ++t) {
                int n = (nt0 + t) * 16 + lr;
                float thA = (float)cbA[n];
                float thB = (float)cbB[n];
                f32x4 cA = {thA, thA, thA, thA};
                f32x4 cB = {thB, thB, thB, thB};
                cA = __builtin_amdgcn_mfma_f32_16x16x32_f16(aA, B[t], cA, 0, 0, 0);
                cB = __builtin_amdgcn_mfma_f32_16x16x32_f16(aB, B[t], cB, 0, 0, 0);
                #pragma unroll
                for (int r = 0; r < 4; ++r) {
                    tRA[t][r] = cA[r];
                    tRB[t][r] = cB[r];
                    tS[0][lqw * 4 + r][n] = (f16)fmaxf(cA[r], 0.f);
                    tS[1][lqw * 4 + r][n] = (f16)fmaxf(cB[r], 0.f);
                }
            }
            load8(mW1f, nt0, l, B);
        }
        barrier_lgkm();
        #pragma unroll
        for (int blk = 0; blk < 2; ++blk) {
            {
                f32x4 aA0 = vzero, aA1 = vzero, aB0 = vzero, aB1 = vzero;
                gemm16<136>(tS[0], tS[1], lr, lqw, B, aA0, aA1, aB0, aB1);
                load8(mW2f + blk * 16384, nt0, l, B);
                const float* bb1p = made_bb1 + blk * 128;
                float bi0 = bb1p[(nt0 + 0) * 16 + lr];
                float bi1 = bb1p[(nt0 + 1) * 16 + lr];
                #pragma unroll
                for (int r = 0; r < 4; ++r) {
                    uS[0][lqw * 4 + r][(nt0 + 0) * 16 + lr] = (f16)fmaxf(aA0[r] + bi0, 0.f);
                    uS[0][lqw * 4 + r][(nt0 + 1) * 16 + lr] = (f16)fmaxf(aA1[r] + bi1, 0.f);
                    uS[1][lqw * 4 + r][(nt0 + 0) * 16 + lr] = (f16)fmaxf(aB0[r] + bi0, 0.f);
                    uS[1][lqw * 4 + r][(nt0 + 1) * 16 + lr] = (f16)fmaxf(aB1[r] + bi1, 0.f);
                }
            }
            barrier_lgkm();
            {
                f32x4 aA0 = vzero, aA1 = vzero, aB0 = vzero, aB1 = vzero;
                gemm16<196>(uS[0], uS[1], lr, lqw, B, aA0, aA1, aB0, aB1);
                if (blk == 0) load8(mW1f + 16384, nt0, l, B);
                const float* bb2p = made_bb2 + blk * 128;
                float bi0 = bb2p[(nt0 + 0) * 16 + lr];
                float bi1 = bb2p[(nt0 + 1) * 16 + lr];
                float gA0 = (float)cbA[128 + blk * 128 + (nt0 + 0) * 16 + lr];
                float gA1 = (float)cbA[128 + blk * 128 + (nt0 + 1) * 16 + lr];
                float gB0 = (float)cbB[128 + blk * 128 + (nt0 + 0) * 16 + lr];
                float gB1 = (float)cbB[128 + blk * 128 + (nt0 + 1) * 16 + lr];
                #pragma unroll
                for (int r = 0; r < 4; ++r) {
                    tRA[0][r] += (aA0[r] + bi0) * gA0;
                    tRA[1][r] += (aA1[r] + bi1) * gA1;
                    tRB[0][r] += (aB0[r] + bi0) * gB0;
                    tRB[1][r] += (aB1[r] + bi1) * gB1;
                    if (blk == 0) {
                        tS[0][lqw * 4 + r][(nt0 + 0) * 16 + lr] = (f16)fmaxf(tRA[0][r], 0.f);
                        tS[0][lqw * 4 + r][(nt0 + 1) * 16 + lr] = (f16)fmaxf(tRA[1][r], 0.f);
                        tS[1][lqw * 4 + r][(nt0 + 0) * 16 + lr] = (f16)fmaxf(tRB[0][r], 0.f);
                        tS[1][lqw * 4 + r][(nt0 + 1) * 16 + lr] = (f16)fmaxf(tRB[1][r], 0.f);
                    } else {
                        tS[0][lqw * 4 + r][(nt0 + 0) * 16 + lr] = (f16)tRA[0][r];
                        tS[0][lqw * 4 + r][(nt0 + 1) * 16 + lr] = (f16)tRA[1][r];
                        tS[1][lqw * 4 + r][(nt0 + 0) * 16 + lr] = (f16)tRB[0][r];
                        tS[1][lqw * 4 + r][(nt0 + 1) * 16 + lr] = (f16)tRB[1][r];
                    }
                }
            }
            barrier_lgkm();
        }
        // MADE Wout: waves 0-1 -> tile 0 (nt=w), waves 2-3 -> tile 1 (nt=w-2)
        {
            const int t2 = w >> 1, nt = w & 1;
            f32x4 po = vzero;
            #pragma unroll
            for (int ks = 0; ks < 4; ++ks) {
                f16x8 a = *(const f16x8*)&tS[t2][lr][ks * 32 + lqw * 8];
                f16x8 b = *(const f16x8*)(mWoutf + nt * 2048 + ks * 512 + l * 8);
                po = __builtin_amdgcn_mfma_f32_16x16x32_f16(a, b, po, 0, 0, 0);
            }
            int n = nt * 16 + lr;
            float bias = made_bout[n];
            #pragma unroll
            for (int r = 0; r < 4; ++r)
                uS[t2][lqw * 4 + r][n] = (f16)(po[r] + bias);
        }
    }
    barrier_lgkm();
    // ---- Gaussian head (both tiles) ----
    {
        const int rw = tid >> 4, d = tid & 15;
        #pragma unroll
        for (int t2 = 0; t2 < 2; ++t2) {
            const int gm = m0 + t2 * 16 + rw, hw = gm >> 2, b = gm & 3;
            float ar0 = (float)uS[t2][rw][2 * d];
            float ar1 = (float)uS[t2][rw][2 * d + 1];
            float s = softplusf(ar0) + 0.001f;
            float zn = s * zO[t2][rw][d] + ar1;
            float ls   = ehw[(size_t)hw * 32 + 16 + d];
            float mean = ehw[(size_t)hw * 32 + d];
            float diff = (zn - mean) * fexpf(-ls);
            float g = flogf(s) - ls - 0.5f * diff * diff + ldS[t2][d][rw];
            g += __shfl_xor(g, 1);
            g += __shfl_xor(g, 2);
            g += __shfl_xor(g, 4);
            g += __shfl_xor(g, 8);
            if (d == 0)
                out[(size_t)b * NHW + hw] = g + luc0 - 14.703016531274762f;
        }
    }
}

extern "C" void kernel_launch(void* const* d_in, const int* in_sizes, int n_in,
                              void* d_out, int out_size, void* d_ws, size_t ws_size,
                              hipStream_t stream) {
    (void)in_sizes; (void)n_in; (void)out_size; (void)ws_size;
    const float* x         = (const float*)d_in[0];
    const float* made_W0   = (const float*)d_in[1];
    const float* made_b0   = (const float*)d_in[2];
    const float* made_ctxW = (const float*)d_in[3];
    const float* made_ctxb = (const float*)d_in[4];
    const float* made_bW1  = (const float*)d_in[5];
    const float* made_bb1  = (const float*)d_in[6];
    const float* made_bW2  = (const float*)d_in[7];
    const float* made_bb2  = (const float*)d_in[8];
    const float* made_bCW  = (const float*)d_in[9];
    const float* made_bCb  = (const float*)d_in[10];
    const float* made_Wout = (const float*)d_in[11];
    const float* made_bout = (const float*)d_in[12];
    const float* sp_Win    = (const float*)d_in[13];
    const float* sp_bin    = (const float*)d_in[14];
    const float* sp_bW1    = (const float*)d_in[15];
    const float* sp_bb1    = (const float*)d_in[16];
    const float* sp_bW2    = (const float*)d_in[17];
    const float* sp_bb2    = (const float*)d_in[18];
    const float* sp_bCW    = (const float*)d_in[19];
    const float* sp_bCb    = (const float*)d_in[20];
    const float* sp_Wout   = (const float*)d_in[21];
    const float* sp_bout   = (const float*)d_in[22];
    const float* sp_uw     = (const float*)d_in[23];
    const float* sp_uh     = (const float*)d_in[24];
    const float* sp_ud     = (const float*)d_in[25];
    const float* lu_lower  = (const float*)d_in[26];
    const float* lu_upper  = (const float*)d_in[27];
    const float* lu_udiag  = (const float*)d_in[28];
    const float* lu_bias   = (const float*)d_in[29];
    const int*   lu_perm   = (const int*)d_in[30];
    const float* enc_W1    = (const float*)d_in[31];
    const float* enc_b1    = (const float*)d_in[32];
    const float* enc_W2    = (const float*)d_in[33];
    const float* enc_b2    = (const float*)d_in[34];
    float* out = (float*)d_out;

    float* ws      = (float*)d_ws;
    float* z       = ws;                               // 36864*16
    float* ehw     = z       + (size_t)NROWS * 16;     // 9216*32
    float* cpb     = ehw     + (size_t)NHW * 32;       // 5*384
    float* epb     = cpb     + 5 * 384;                // 160 (pad 192)
    float* idk     = epb     + 192;                    // 4*8*48
    float* beff    = idk     + 1536;                   // 4*128
    float* luc     = beff    + 512;                    // 1 (pad 16)
    f16*   ctxoutf = (f16*)(luc + 16);                 // 5*9216*384 f16
    f16*   fW1f    = ctxoutf + (size_t)5 * NHW * 384;  // 8*16384
    f16*   fW2f    = fW1f    + 8 * 16384;              // 8*16384
    f16*   mW1f    = fW2f    + 8 * 16384;              // 2*16384
    f16*   mW2f    = mW1f    + 2 * 16384;              // 2*16384
    f16*   fWoutf  = mW2f    + 2 * 16384;              // 4*24576
    f16*   mWoutf  = fWoutf  + 4 * 24576;              // 4096
    f16*   weffF   = mWoutf  + 4096;                   // 4*4096
    f16*   mlutF   = weffF   + 4 * 4096;               // 4*512
    f16*   minf    = mlutF   + 4 * 512;                // 4096
    f16*   encW1f  = minf    + 4096;                   // 16384
    f16*   encW2f  = encW1f  + 16384;                  // 4096
    f16*   cfrag   = encW2f  + 4096;                   // 5*49152

    dim3 B(256);
    setup_kernel<<<5124, B, 0, stream>>>(
        x,
        sp_bW1, sp_bW2, made_bW1, made_bW2, sp_Wout, made_Wout, sp_Win, made_W0,
        sp_bCW, made_ctxW, made_bCW, sp_bin, sp_bCb, made_ctxb, made_b0, made_bCb,
        enc_W1, enc_b1, enc_W2, enc_b2,
        sp_uw, sp_uh, sp_ud, lu_lower, lu_upper, lu_udiag, lu_bias, lu_perm,
        z,
        fW1f, fW2f, mW1f, mW2f, fWoutf, mWoutf, minf, cfrag, cpb,
        encW1f, encW2f, epb,
        weffF, mlutF, beff, idk, luc);

    ctx_mfma<<<dim3(576, 3), B, 0, stream>>>(cfrag, cpb, encW1f, encW2f, epb,
                                             ctxoutf, ehw);

    mega_all<<<1152, B, 0, stream>>>(z, ctxoutf, weffF, mlutF, beff, minf,
                                     fW1f, fW2f, mW1f, mW2f, fWoutf, mWoutf,
                                     sp_bb1, sp_bb2, made_bb1, made_bb2,
                                     sp_bout, made_bout,
                                     lu_bias, idk, luc, ehw, out);
}

// Round 24
// 209.473 us; speedup vs baseline: 1.1277x; 1.1154x over previous
//
#include <hip/hip_runtime.h>
#include <math.h>

#define NHW   9216     // 96*96
#define NROWS 36864    // NHW*4

typedef _Float16 f16;
typedef _Float16 f16x8 __attribute__((ext_vector_type(8)));
typedef float    f32x4 __attribute__((ext_vector_type(4)));

// fast transcendentals (hardware v_exp_f32 / v_log_f32; rel err ~1e-5, fine vs thr 10.3)
__device__ __forceinline__ float fexpf(float x) { return __expf(x); }
__device__ __forceinline__ float flogf(float x) { return __logf(x); }

__device__ __forceinline__ float softplusf(float x) {
    return fmaxf(x, 0.f) + log1pf(fexpf(-fabsf(x)));
}

// LDS-only barrier: global loads into private VGPRs stay in flight across it.
__device__ __forceinline__ void barrier_lgkm() {
    __builtin_amdgcn_sched_barrier(0);
    asm volatile("s_waitcnt lgkmcnt(0)" ::: "memory");
    __builtin_amdgcn_s_barrier();
    __builtin_amdgcn_sched_barrier(0);
}

// ---------------- knots helper ----------------
__device__ __forceinline__ void knots8(const float* __restrict__ u, float* c, float* w) {
    float mx = u[0];
    #pragma unroll
    for (int k = 1; k < 8; ++k) mx = fmaxf(mx, u[k]);
    float e[8]; float s = 0.f;
    #pragma unroll
    for (int k = 0; k < 8; ++k) { e[k] = fexpf(u[k] - mx); s += e[k]; }
    float inv = 1.f / s;
    c[0] = -3.f;
    float cum = 0.f;
    #pragma unroll
    for (int k = 0; k < 8; ++k) {
        float v = 0.001f + 0.992f * e[k] * inv;
        cum += v;
        c[k + 1] = cum * 6.f - 3.f;
    }
    c[8] = 3.f;
    #pragma unroll
    for (int k = 0; k < 8; ++k) w[k] = c[k + 1] - c[k];
}

// ---------------- merged setup kernel: snorm | pack | prep ----------------
// blocks [0,2304): snorm tiles; [2304,5049): pack (flat 702496 elems);
// [5049,5123): prep fragment work (each recomputes Mlu in LDS); block 5123: idk+luc.
__global__ __launch_bounds__(256) void setup_kernel(
    const float* __restrict__ x,
    const float* __restrict__ sp_bW1, const float* __restrict__ sp_bW2,
    const float* __restrict__ made_bW1, const float* __restrict__ made_bW2,
    const float* __restrict__ sp_Wout, const float* __restrict__ made_Wout,
    const float* __restrict__ sp_Win, const float* __restrict__ made_W0,
    const float* __restrict__ sp_bCW, const float* __restrict__ made_ctxW,
    const float* __restrict__ made_bCW,
    const float* __restrict__ sp_bin, const float* __restrict__ sp_bCb,
    const float* __restrict__ made_ctxb, const float* __restrict__ made_b0,
    const float* __restrict__ made_bCb,
    const float* __restrict__ enc_W1, const float* __restrict__ enc_b1,
    const float* __restrict__ enc_W2, const float* __restrict__ enc_b2,
    const float* __restrict__ sp_uw, const float* __restrict__ sp_uh,
    const float* __restrict__ sp_ud,
    const float* __restrict__ lu_lower, const float* __restrict__ lu_upper,
    const float* __restrict__ lu_udiag, const float* __restrict__ lu_bias,
    const int*   __restrict__ lu_perm,
    float* __restrict__ z,
    f16* __restrict__ fW1f, f16* __restrict__ fW2f,
    f16* __restrict__ mW1f, f16* __restrict__ mW2f,
    f16* __restrict__ fWoutf, f16* __restrict__ mWoutf,
    f16* __restrict__ minf,
    f16* __restrict__ cfrag, float* __restrict__ cpb,
    f16* __restrict__ encW1f, f16* __restrict__ encW2f, float* __restrict__ epb,
    f16* __restrict__ weffF, f16* __restrict__ mlutF,
    float* __restrict__ beff, float* __restrict__ idk, float* __restrict__ luc)
{
    __shared__ float sS[33][34];
    __shared__ float sMlu[4][16][16];
    const int bid = blockIdx.x;
    const int t = threadIdx.x;

    if (bid < 2304) {
        const int bs   = bid / 36;
        const int tile = bid % 36;
        const int ti = tile / 6, tj = tile % 6;
        const int i0 = ti * 16, j0 = tj * 16;
        const int b = bs >> 4, s = bs & 15;
        const float* xb = x + (size_t)(bs * 3) * 36864;
        for (int e = t; e < 33 * 33; e += 256) {
            int row = e / 33, col = e % 33;
            int hh = 2 * i0 - 1 + row, ww = 2 * j0 - 1 + col;
            float acc = 0.f;
            if (hh >= 0 && hh < 192 && ww >= 0 && ww < 192) {
                #pragma unroll
                for (int c = 0; c < 3; ++c) {
                    float v = xb[c * 36864 + hh * 192 + ww];
                    acc += v * v;
                }
            }
            sS[row][col] = acc;
        }
        __syncthreads();
        const int oi = t >> 4, oj = t & 15;
        float sum = 0.f;
        #pragma unroll
        for (int dr = 0; dr < 3; ++dr)
            #pragma unroll
            for (int dc = 0; dc < 3; ++dc)
                sum += sS[2 * oi + dr][2 * oj + dc];
        const int i = i0 + oi, j = j0 + oj;
        z[((size_t)(i * 96 + j) * 4 + b) * 16 + s] = sqrtf(sum);
        return;
    }

    if (bid < 5049) {
        int idx = (bid - 2304) * 256 + t;
        if (idx < 131072) {
            int e = idx;
            int mtx = e >> 14, f = e & 16383;
            int nt = f >> 11, ks = (f >> 9) & 3, l = (f >> 3) & 63, j = f & 7;
            int n = nt * 16 + (l & 15), k = ks * 32 + ((l >> 4) & 3) * 8 + j;
            fW1f[e] = (f16)sp_bW1[mtx * 16384 + n * 128 + k];
            return;
        }
        idx -= 131072;
        if (idx < 131072) {
            int e = idx;
            int mtx = e >> 14, f = e & 16383;
            int nt = f >> 11, ks = (f >> 9) & 3, l = (f >> 3) & 63, j = f & 7;
            int n = nt * 16 + (l & 15), k = ks * 32 + ((l >> 4) & 3) * 8 + j;
            fW2f[e] = (f16)sp_bW2[mtx * 16384 + n * 128 + k];
            return;
        }
        idx -= 131072;
        if (idx < 32768) {
            int e = idx;
            int mtx = e >> 14, f = e & 16383;
            int nt = f >> 11, ks = (f >> 9) & 3, l = (f >> 3) & 63, j = f & 7;
            int n = nt * 16 + (l & 15), k = ks * 32 + ((l >> 4) & 3) * 8 + j;
            mW1f[e] = ((n % 15) >= (k % 15)) ? (f16)made_bW1[mtx * 16384 + n * 128 + k] : (f16)0.f;
            return;
        }
        idx -= 32768;
        if (idx < 32768) {
            int e = idx;
            int mtx = e >> 14, f = e & 16383;
            int nt = f >> 11, ks = (f >> 9) & 3, l = (f >> 3) & 63, j = f & 7;
            int n = nt * 16 + (l & 15), k = ks * 32 + ((l >> 4) & 3) * 8 + j;
            mW2f[e] = ((n % 15) >= (k % 15)) ? (f16)made_bW2[mtx * 16384 + n * 128 + k] : (f16)0.f;
            return;
        }
        idx -= 32768;
        if (idx < 98304) {
            int e = idx;
            int s = e / 24576, f = e % 24576;
            int nt = f >> 11, ks = (f >> 9) & 3, l = (f >> 3) & 63, j = f & 7;
            int n = nt * 16 + (l & 15), k = ks * 32 + ((l >> 4) & 3) * 8 + j;
            fWoutf[e] = (n < 184) ? (f16)sp_Wout[s * 23552 + n * 128 + k] : (f16)0.f;
            return;
        }
        idx -= 98304;
        if (idx < 4096) {
            int f = idx;
            int nt = f >> 11, ks = (f >> 9) & 3, l = (f >> 3) & 63, j = f & 7;
            int n = nt * 16 + (l & 15), k = ks * 32 + ((l >> 4) & 3) * 8 + j;
            mWoutf[idx] = (((n & 15) > (k % 15)) && n < 32) ? (f16)made_Wout[n * 128 + k] : (f16)0.f;
            return;
        }
        idx -= 4096;
        if (idx < 4096) {
            int f = idx;
            int nt = f >> 9, l = (f >> 3) & 63, j = f & 7;
            int n = nt * 16 + (l & 15), k = ((l >> 4) & 3) * 8 + j;
            minf[idx] = (k < 16 && (n % 15) >= k) ? (f16)made_W0[n * 16 + k] : (f16)0.f;
            return;
        }
        idx -= 4096;
        if (idx < 245760) {
            int e = idx;
            int s = e / 49152, f = e % 49152;
            int nt = f >> 11, ks = (f >> 9) & 3, l = (f >> 3) & 63, j = f & 7;
            int n = nt * 16 + (l & 15), k = ks * 32 + ((l >> 4) & 3) * 8 + j;
            float v;
            if (s < 4) {
                if (n < 128)      v = sp_Win[s * 17408 + n * 136 + 8 + k];
                else if (n < 256) v = sp_bCW[(size_t)(s * 2 + 0) * 16384 + (n - 128) * 128 + k];
                else              v = sp_bCW[(size_t)(s * 2 + 1) * 16384 + (n - 256) * 128 + k];
            } else {
                if (n < 128)      v = made_ctxW[n * 128 + k];
                else if (n < 256) v = made_bCW[(n - 128) * 128 + k];
                else              v = made_bCW[16384 + (n - 256) * 128 + k];
            }
            cfrag[e] = (f16)v;
            return;
        }
        idx -= 245760;
        if (idx < 1920) {
            int e = idx;
            int s = e / 384, n = e % 384;
            float v;
            if (s < 4) {
                if (n < 128)      v = sp_bin[s * 128 + n];
                else if (n < 256) v = sp_bCb[(s * 2 + 0) * 128 + (n - 128)];
                else              v = sp_bCb[(s * 2 + 1) * 128 + (n - 256)];
            } else {
                if (n < 128)      v = made_ctxb[n] + made_b0[n];
                else if (n < 256) v = made_bCb[n - 128];
                else              v = made_bCb[128 + (n - 256)];
            }
            cpb[e] = v;
            return;
        }
        idx -= 1920;
        if (idx < 16384) {
            int f = idx;
            int nt = f >> 11, ks = (f >> 9) & 3, l = (f >> 3) & 63, j = f & 7;
            int n = nt * 16 + (l & 15), k = ks * 32 + ((l >> 4) & 3) * 8 + j;
            encW1f[idx] = (f16)enc_W1[n * 128 + k];
            return;
        }
        idx -= 16384;
        if (idx < 4096) {
            int f = idx;
            int nt = f >> 11, ks = (f >> 9) & 3, l = (f >> 3) & 63, j = f & 7;
            int n = nt * 16 + (l & 15), k = ks * 32 + ((l >> 4) & 3) * 8 + j;
            encW2f[idx] = (n < 32) ? (f16)enc_W2[n * 128 + k] : (f16)0.f;
            return;
        }
        idx -= 4096;
        if (idx < 160) {
            epb[idx] = (idx < 128) ? enc_b1[idx] : enc_b2[idx - 128];
        }
        return;
    }

    if (bid == 5123) {
        if (t < 32) {
            int s = t >> 3, dim = t & 7;
            float* o = idk + (s * 8 + dim) * 48;
            float c[9], w[8];
            knots8(sp_uw + s * 64 + dim * 8, c, w);
            #pragma unroll
            for (int k = 0; k < 9; ++k) o[k] = c[k];
            #pragma unroll
            for (int k = 0; k < 8; ++k) o[9 + k] = w[k];
            knots8(sp_uh + s * 64 + dim * 8, c, w);
            #pragma unroll
            for (int k = 0; k < 9; ++k) o[17 + k] = c[k];
            #pragma unroll
            for (int k = 0; k < 8; ++k) o[26 + k] = w[k];
            o[34] = 1.f; o[42] = 1.f;
            #pragma unroll
            for (int k = 0; k < 7; ++k) o[35 + k] = 0.001f + softplusf(sp_ud[s * 56 + dim * 7 + k]);
        } else if (t == 32) {
            float c0 = 0.f;
            for (int k = 0; k < 64; ++k)
                c0 += flogf(softplusf(lu_udiag[k]) + 0.001f);
            luc[0] = c0;
        }
        return;
    }

    // ---- prep fragment blocks [5049,5123) ----
    {
        if (t < 64) {
            int s = t >> 4, d = t & 15;
            const float* L  = lu_lower + s * 256;
            const float* U  = lu_upper + s * 256;
            const float* ud = lu_udiag + s * 16;
            const int*   pm = lu_perm + s * 16;
            for (int c = 0; c < 16; ++c) {
                float m = 0.f;
                if (c > d)       m += U[d * 16 + c];
                else if (c == d) m += softplusf(ud[d]) + 0.001f;
                for (int e = 0; e < d && e <= c; ++e) {
                    float u = (c > e) ? U[e * 16 + c] : (softplusf(ud[e]) + 0.001f);
                    m += L[d * 16 + e] * u;
                }
                sMlu[s][d][pm[c]] = m;
            }
        }
        __syncthreads();
        int idx = (bid - 5049) * 256 + t;
        if (idx < 16384) {
            int e = idx;
            int s = e >> 12, f = e & 4095;
            int nt = f >> 9, l = (f >> 3) & 63, j = f & 7;
            int n = nt * 16 + (l & 15), k = ((l >> 4) & 3) * 8 + j;
            float v = 0.f;
            if (k < 16) {
                #pragma unroll
                for (int p = 0; p < 8; ++p)
                    v += sMlu[s][2 * p][k] * sp_Win[s * 17408 + n * 136 + p];
            }
            weffF[e] = (f16)v;
        } else if (idx < 18432) {
            int e = idx - 16384;
            int s = e >> 9, f = e & 511;
            int l = f >> 3, j = f & 7;
            int n = l & 15, k = (l >> 4) * 8 + j;
            mlutF[e] = (k < 16) ? (f16)sMlu[s][n][k] : (f16)0.f;
        } else if (idx < 18944) {
            int e = idx - 18432;
            int s = e >> 7, n = e & 127;
            float v = 0.f;
            #pragma unroll
            for (int p = 0; p < 8; ++p)
                v += lu_bias[s * 16 + 2 * p] * sp_Win[s * 17408 + n * 136 + p];
            beff[e] = v;
        }
        return;
    }
}

// ---------------- ctx-chain MFMA: 2 slices per block ----------------
__global__ __launch_bounds__(256) void ctx_mfma(
    const f16* __restrict__ cfrag,
    const float* __restrict__ cpb,
    const f16* __restrict__ encW1f, const f16* __restrict__ encW2f,
    const float* __restrict__ epb,
    f16* __restrict__ ctxoutf, float* __restrict__ ehw)
{
    __shared__ alignas(16) f16 cS[16][136];
    __shared__ alignas(16) f16 hS[16][136];
    const int tid = threadIdx.x, w = tid >> 6, l = tid & 63;
    const int m0 = blockIdx.x * 16;
    const int sy = blockIdx.y;
    const int lr = l & 15, lq = l >> 4;
    #pragma unroll
    for (int it = 0; it < 2; ++it) {
        int e = tid + it * 256;
        int r = e >> 5, c4 = (e & 31) * 4;
        int hw = m0 + r;
        int ii = hw / 96, jj = hw % 96;
        #pragma unroll
        for (int q = 0; q < 4; ++q) {
            int c = c4 + q;
            int pos = (c < 64) ? ii : jj;
            int cc = c & 63;
            int k = cc >> 1;
            float invf = exp2f((float)k * -0.4152410118609203f);  // 10000^(-k/32)
            float v = (float)pos * invf;
            cS[r][c] = (f16)((cc & 1) ? cosf(v) : sinf(v));
        }
    }
    __syncthreads();
    const f32x4 vzero = {0.f, 0.f, 0.f, 0.f};
    #pragma unroll
    for (int sub = 0; sub < 2; ++sub) {
        const int s = sy * 2 + sub;
        if (s < 5) {
            f32x4 acc[6];
            #pragma unroll
            for (int q = 0; q < 6; ++q) acc[q] = vzero;
            const f16* wb = cfrag + (size_t)s * 49152;
            #pragma unroll
            for (int ks = 0; ks < 4; ++ks) {
                f16x8 a = *(const f16x8*)&cS[lr][ks * 32 + lq * 8];
                #pragma unroll
                for (int q = 0; q < 6; ++q) {
                    int g = w * 6 + q;
                    f16x8 b = *(const f16x8*)(wb + (size_t)((g * 4 + ks) * 64 + l) * 8);
                    acc[q] = __builtin_amdgcn_mfma_f32_16x16x32_f16(a, b, acc[q], 0, 0, 0);
                }
            }
            #pragma unroll
            for (int q = 0; q < 6; ++q) {
                int g = w * 6 + q, n = g * 16 + lr;
                float bias = cpb[s * 384 + n];
                #pragma unroll
                for (int r = 0; r < 4; ++r) {
                    float val = acc[q][r] + bias;
                    if (n >= 128) val = 1.f / (1.f + fexpf(-val));
                    ctxoutf[(size_t)s * NHW * 384 + (size_t)(m0 + lq * 4 + r) * 384 + n] = (f16)val;
                }
            }
        } else {
            f32x4 acc0 = vzero, acc1 = vzero;
            #pragma unroll
            for (int ks = 0; ks < 4; ++ks) {
                f16x8 a = *(const f16x8*)&cS[lr][ks * 32 + lq * 8];
                f16x8 b0 = *(const f16x8*)(encW1f + (((w * 2 + 0) * 4 + ks) * 64 + l) * 8);
                f16x8 b1 = *(const f16x8*)(encW1f + (((w * 2 + 1) * 4 + ks) * 64 + l) * 8);
                acc0 = __builtin_amdgcn_mfma_f32_16x16x32_f16(a, b0, acc0, 0, 0, 0);
                acc1 = __builtin_amdgcn_mfma_f32_16x16x32_f16(a, b1, acc1, 0, 0, 0);
            }
            {
                int n0 = (w * 2 + 0) * 16 + lr, n1 = (w * 2 + 1) * 16 + lr;
                float bi0 = epb[n0], bi1 = epb[n1];
                #pragma unroll
                for (int r = 0; r < 4; ++r) {
                    float v0 = acc0[r] + bi0, v1 = acc1[r] + bi1;
                    hS[lq * 4 + r][n0] = (f16)(v0 / (1.f + fexpf(-v0)));
                    hS[lq * 4 + r][n1] = (f16)(v1 / (1.f + fexpf(-v1)));
                }
            }
            __syncthreads();
            if (w < 2) {
                f32x4 po = vzero;
                #pragma unroll
                for (int ks = 0; ks < 4; ++ks) {
                    f16x8 a = *(const f16x8*)&hS[lr][ks * 32 + lq * 8];
                    f16x8 b = *(const f16x8*)(encW2f + ((w * 4 + ks) * 64 + l) * 8);
                    po = __builtin_amdgcn_mfma_f32_16x16x32_f16(a, b, po, 0, 0, 0);
                }
                int n = w * 16 + lr;
                float bias = epb[128 + n];
                #pragma unroll
                for (int r = 0; r < 4; ++r)
                    ehw[(size_t)(m0 + lq * 4 + r) * 32 + n] = po[r] + bias;
            }
        }
    }
}

// ---------------- rational-quadratic spline ----------------
__device__ __forceinline__ void rqs_core(float x, const float* cw, const float* wd,
                                         const float* ch, const float* hg, const float* dd,
                                         float& y, float& ld) {
    bool inside = (x >= -3.f) && (x <= 3.f);
    float xc = fminf(fmaxf(x, -3.f), 3.f);
    float cwk = cw[0], wk = wd[0], chk = ch[0], hk = hg[0], d0 = dd[0], d1 = dd[1];
    #pragma unroll
    for (int k = 1; k < 8; ++k) {
        if (xc >= cw[k]) { cwk = cw[k]; wk = wd[k]; chk = ch[k]; hk = hg[k]; d0 = dd[k]; d1 = dd[k + 1]; }
    }
    float dl = hk / wk;
    float th = (xc - cwk) / wk;
    float t1 = th * (1.f - th);
    float den = dl + (d0 + d1 - 2.f * dl) * t1;
    float yy = chk + hk * (dl * th * th + d0 * t1) / den;
    float om = 1.f - th;
    float dnum = dl * dl * (d1 * th * th + 2.f * dl * t1 + d0 * om * om);
    float lld = flogf(dnum) - 2.f * flogf(den);
    y  = inside ? yy : x;
    ld = inside ? lld : 0.f;
}

__device__ __forceinline__ void rqs1(float x,
                                     const float* __restrict__ uw,
                                     const float* __restrict__ uh,
                                     const float* __restrict__ ud,
                                     float& y, float& ld) {
    float cw[9], wd[8], ch[9], hg[8], dd[9];
    knots8(uw, cw, wd);
    knots8(uh, ch, hg);
    dd[0] = 1.f; dd[8] = 1.f;
    #pragma unroll
    for (int k = 0; k < 7; ++k) dd[k + 1] = 0.001f + softplusf(ud[k]);
    rqs_core(x, cw, wd, ch, hg, dd, y, ld);
}

__device__ __forceinline__ void rqs1_pre(float x, const float* __restrict__ kn,
                                         float& y, float& ld) {
    float cw[9], wd[8], ch[9], hg[8], dd[9];
    #pragma unroll
    for (int k = 0; k < 9; ++k) cw[k] = kn[k];
    #pragma unroll
    for (int k = 0; k < 8; ++k) wd[k] = kn[9 + k];
    #pragma unroll
    for (int k = 0; k < 9; ++k) ch[k] = kn[17 + k];
    #pragma unroll
    for (int k = 0; k < 8; ++k) hg[k] = kn[26 + k];
    #pragma unroll
    for (int k = 0; k < 9; ++k) dd[k] = kn[34 + k];
    rqs_core(x, cw, wd, ch, hg, dd, y, ld);
}

// ---------------- prefetch helpers ----------------
__device__ __forceinline__ void load8(const f16* __restrict__ w, int nt0, int l,
                                      f16x8 B[8]) {
    #pragma unroll
    for (int q = 0; q < 2; ++q)
        #pragma unroll
        for (int ks = 0; ks < 4; ++ks)
            B[q * 4 + ks] = *(const f16x8*)(w + (nt0 + q) * 2048 + ks * 512 + l * 8);
}

// two-tile GEMM: shared B-frags, A-frags from both tiles' LDS (stride-templated)
template<int S>
__device__ __forceinline__ void gemm16(const f16 (*__restrict__ SA)[S],
                                       const f16 (*__restrict__ SB)[S],
                                       int lr, int lqw, const f16x8 B[8],
                                       f32x4& aA0, f32x4& aA1, f32x4& aB0, f32x4& aB1) {
    __builtin_amdgcn_s_setprio(1);
    #pragma unroll
    for (int ks = 0; ks < 4; ++ks) {
        f16x8 aA = *(const f16x8*)&SA[lr][ks * 32 + lqw * 8];
        f16x8 aB = *(const f16x8*)&SB[lr][ks * 32 + lqw * 8];
        aA0 = __builtin_amdgcn_mfma_f32_16x16x32_f16(aA, B[ks], aA0, 0, 0, 0);
        aB0 = __builtin_amdgcn_mfma_f32_16x16x32_f16(aB, B[ks], aB0, 0, 0, 0);
        aA1 = __builtin_amdgcn_mfma_f32_16x16x32_f16(aA, B[4 + ks], aA1, 0, 0, 0);
        aB1 = __builtin_amdgcn_mfma_f32_16x16x32_f16(aB, B[4 + ks], aB1, 0, 0, 0);
    }
    __builtin_amdgcn_s_setprio(0);
}

// ---------------- merged pipeline: TWO 16-row tiles per block ----------------
// Union buffer stride padded 196 -> 200: row stride 400 B = 25*16 keeps f16x8
// LDS reads 16B-aligned (ds_read_b128); 400 B = 100 dwords = 4 banks/row (free
// 2-way pattern). r23's stride 196 (392 B) broke alignment and cost 17%.
__global__ __launch_bounds__(256) void mega_all(
    const float* __restrict__ zg,
    const f16*  __restrict__ ctxoutf,   // [5][9216][384]
    const f16*  __restrict__ weffF,     // [4][4096]
    const f16*  __restrict__ mlutF,     // [4][512]
    const float* __restrict__ beffv,    // [4][128]
    const f16*  __restrict__ minf,      // [4096]
    const f16*  __restrict__ fW1f,      // [4][2][16384]
    const f16*  __restrict__ fW2f,
    const f16*  __restrict__ mW1f,      // [2][16384]
    const f16*  __restrict__ mW2f,
    const f16*  __restrict__ fWoutf,    // [4][24576]
    const f16*  __restrict__ mWoutf,    // [4096]
    const float* __restrict__ sp_bb1,   // [4][2][128]
    const float* __restrict__ sp_bb2,
    const float* __restrict__ made_bb1, // [2][128]
    const float* __restrict__ made_bb2,
    const float* __restrict__ sp_bout,  // [4][184]
    const float* __restrict__ made_bout,// [32]
    const float* __restrict__ lu_bias,  // [4][16]
    const float* __restrict__ idk,      // [4][8][48]
    const float* __restrict__ luc,      // [1]
    const float* __restrict__ ehw,      // [9216][32]
    float* __restrict__ out)            // [4][9216]
{
    __shared__ alignas(16) f16 tS[2][16][136];
    __shared__ alignas(16) f16 uS[2][16][200];   // union: residual hidden (cols<128) / WOUT out (cols<196)
    __shared__ alignas(16) f16 zS[2][16][32];
    __shared__ float zlu[2][16][17];
    __shared__ float zO[2][16][17];
    __shared__ float ldS[2][16][17];
    const int tid = threadIdx.x;
    const int w   = tid >> 6;
    const int l   = tid & 63;
    const int lr  = l & 15;
    const int lqw = l >> 4;
    const int m0  = blockIdx.x * 32;
    const int hwA = (m0 >> 2) + lqw;
    const int hwB = hwA + 4;
    const int nt0 = w * 2;
    const f32x4 vzero = {0.f, 0.f, 0.f, 0.f};

    #pragma unroll
    for (int it = 0; it < 2; ++it) {
        int e = tid + it * 256;
        int rr = e >> 4, d2 = e & 15;
        int t2 = rr >> 4, r2 = rr & 15;
        zS[t2][r2][d2] = (f16)zg[(size_t)(m0 + rr) * 16 + d2];
        zS[t2][r2][16 + d2] = (f16)0.f;
    }
    float luc0 = luc[0];
    float ldA = 0.f, ldB = 0.f;

    f16x8 B[8];
    f16x8 bml;
    B[0] = *(const f16x8*)(weffF + 3 * 4096 + ((nt0 + 0) * 64 + l) * 8);
    B[1] = *(const f16x8*)(weffF + 3 * 4096 + ((nt0 + 1) * 64 + l) * 8);
    bml  = *(const f16x8*)(mlutF + 3 * 512 + l * 8);
    barrier_lgkm();

    const int n0q = (w + 0) * 16 + lr, n1q = (w + 4) * 16 + lr, n2q = (w + 8) * 16 + lr;

    float tRA[2][4], tRB[2][4];

    for (int i = 3; i >= 0; --i) {
        const f16* cbA = ctxoutf + (size_t)i * NHW * 384 + (size_t)hwA * 384;
        const f16* cbB = ctxoutf + (size_t)i * NHW * 384 + (size_t)hwB * 384;
        // ---- IN ----
        {
            f16x8 aA = *(const f16x8*)&zS[0][lr][lqw * 8];
            f16x8 aB = *(const f16x8*)&zS[1][lr][lqw * 8];
            if (w < 2) {
                float bl = lu_bias[i * 16 + lr];
                f32x4 c = {bl, bl, bl, bl};
                c = __builtin_amdgcn_mfma_f32_16x16x32_f16(w == 0 ? aA : aB, bml, c, 0, 0, 0);
                #pragma unroll
                for (int r = 0; r < 4; ++r)
                    zlu[w][lqw * 4 + r][lr] = c[r];
            }
            #pragma unroll
            for (int t = 0; t < 2; ++t) {
                int n = (nt0 + t) * 16 + lr;
                float bf = beffv[i * 128 + n];
                float ciA = (float)cbA[n] + bf;
                float ciB = (float)cbB[n] + bf;
                f32x4 cA = {ciA, ciA, ciA, ciA};
                f32x4 cB = {ciB, ciB, ciB, ciB};
                cA = __builtin_amdgcn_mfma_f32_16x16x32_f16(aA, B[t], cA, 0, 0, 0);
                cB = __builtin_amdgcn_mfma_f32_16x16x32_f16(aB, B[t], cB, 0, 0, 0);
                #pragma unroll
                for (int r = 0; r < 4; ++r) {
                    tRA[t][r] = cA[r];
                    tRB[t][r] = cB[r];
                    tS[0][lqw * 4 + r][n] = (f16)fmaxf(cA[r], 0.f);
                    tS[1][lqw * 4 + r][n] = (f16)fmaxf(cB[r], 0.f);
                }
            }
            load8(fW1f + (size_t)i * 32768, nt0, l, B);
        }
        barrier_lgkm();
        // ---- residual blocks ----
        #pragma unroll
        for (int blk = 0; blk < 2; ++blk) {
            // W1
            {
                f32x4 aA0 = vzero, aA1 = vzero, aB0 = vzero, aB1 = vzero;
                gemm16<136>(tS[0], tS[1], lr, lqw, B, aA0, aA1, aB0, aB1);
                load8(fW2f + (size_t)i * 32768 + blk * 16384, nt0, l, B);
                const float* bb1p = sp_bb1 + i * 256 + blk * 128;
                float bi0 = bb1p[(nt0 + 0) * 16 + lr];
                float bi1 = bb1p[(nt0 + 1) * 16 + lr];
                #pragma unroll
                for (int r = 0; r < 4; ++r) {
                    uS[0][lqw * 4 + r][(nt0 + 0) * 16 + lr] = (f16)fmaxf(aA0[r] + bi0, 0.f);
                    uS[0][lqw * 4 + r][(nt0 + 1) * 16 + lr] = (f16)fmaxf(aA1[r] + bi1, 0.f);
                    uS[1][lqw * 4 + r][(nt0 + 0) * 16 + lr] = (f16)fmaxf(aB0[r] + bi0, 0.f);
                    uS[1][lqw * 4 + r][(nt0 + 1) * 16 + lr] = (f16)fmaxf(aB1[r] + bi1, 0.f);
                }
            }
            barrier_lgkm();
            // W2
            {
                f32x4 aA0 = vzero, aA1 = vzero, aB0 = vzero, aB1 = vzero;
                gemm16<200>(uS[0], uS[1], lr, lqw, B, aA0, aA1, aB0, aB1);
                if (blk == 0) load8(fW1f + (size_t)i * 32768 + 16384, nt0, l, B);
                else {
                    const f16* wo = fWoutf + (size_t)i * 24576;
                    #pragma unroll
                    for (int t2 = 0; t2 < 2; ++t2)
                        #pragma unroll
                        for (int ks = 0; ks < 4; ++ks)
                            B[t2 * 4 + ks] = *(const f16x8*)(wo + (w + t2 * 4) * 2048 + ks * 512 + l * 8);
                }
                const float* bb2p = sp_bb2 + i * 256 + blk * 128;
                float bi0 = bb2p[(nt0 + 0) * 16 + lr];
                float bi1 = bb2p[(nt0 + 1) * 16 + lr];
                float gA0 = (float)cbA[128 + blk * 128 + (nt0 + 0) * 16 + lr];
                float gA1 = (float)cbA[128 + blk * 128 + (nt0 + 1) * 16 + lr];
                float gB0 = (float)cbB[128 + blk * 128 + (nt0 + 0) * 16 + lr];
                float gB1 = (float)cbB[128 + blk * 128 + (nt0 + 1) * 16 + lr];
                #pragma unroll
                for (int r = 0; r < 4; ++r) {
                    tRA[0][r] += (aA0[r] + bi0) * gA0;
                    tRA[1][r] += (aA1[r] + bi1) * gA1;
                    tRB[0][r] += (aB0[r] + bi0) * gB0;
                    tRB[1][r] += (aB1[r] + bi1) * gB1;
                    if (blk == 0) {
                        tS[0][lqw * 4 + r][(nt0 + 0) * 16 + lr] = (f16)fmaxf(tRA[0][r], 0.f);
                        tS[0][lqw * 4 + r][(nt0 + 1) * 16 + lr] = (f16)fmaxf(tRA[1][r], 0.f);
                        tS[1][lqw * 4 + r][(nt0 + 0) * 16 + lr] = (f16)fmaxf(tRB[0][r], 0.f);
                        tS[1][lqw * 4 + r][(nt0 + 1) * 16 + lr] = (f16)fmaxf(tRB[1][r], 0.f);
                    } else {
                        tS[0][lqw * 4 + r][(nt0 + 0) * 16 + lr] = (f16)tRA[0][r];
                        tS[0][lqw * 4 + r][(nt0 + 1) * 16 + lr] = (f16)tRA[1][r];
                        tS[1][lqw * 4 + r][(nt0 + 0) * 16 + lr] = (f16)tRB[0][r];
                        tS[1][lqw * 4 + r][(nt0 + 1) * 16 + lr] = (f16)tRB[1][r];
                    }
                }
            }
            barrier_lgkm();
        }
        // ---- WOUT -> uS (union; both tiles; B holds nt w, w+4) ----
        {
            f32x4 pA0 = vzero, pA1 = vzero, pA2 = vzero;
            f32x4 pB0 = vzero, pB1 = vzero, pB2 = vzero;
            const f16* wo = fWoutf + (size_t)i * 24576;
            __builtin_amdgcn_s_setprio(1);
            #pragma unroll
            for (int ks = 0; ks < 4; ++ks) {
                f16x8 aA = *(const f16x8*)&tS[0][lr][ks * 32 + lqw * 8];
                f16x8 aB = *(const f16x8*)&tS[1][lr][ks * 32 + lqw * 8];
                pA0 = __builtin_amdgcn_mfma_f32_16x16x32_f16(aA, B[ks], pA0, 0, 0, 0);
                pB0 = __builtin_amdgcn_mfma_f32_16x16x32_f16(aB, B[ks], pB0, 0, 0, 0);
                pA1 = __builtin_amdgcn_mfma_f32_16x16x32_f16(aA, B[4 + ks], pA1, 0, 0, 0);
                pB1 = __builtin_amdgcn_mfma_f32_16x16x32_f16(aB, B[4 + ks], pB1, 0, 0, 0);
                f16x8 b2 = *(const f16x8*)(wo + (w + 8) * 2048 + ks * 512 + l * 8);
                pA2 = __builtin_amdgcn_mfma_f32_16x16x32_f16(aA, b2, pA2, 0, 0, 0);
                pB2 = __builtin_amdgcn_mfma_f32_16x16x32_f16(aB, b2, pB2, 0, 0, 0);
            }
            __builtin_amdgcn_s_setprio(0);
            if (i > 0) {
                B[0] = *(const f16x8*)(weffF + (i - 1) * 4096 + ((nt0 + 0) * 64 + l) * 8);
                B[1] = *(const f16x8*)(weffF + (i - 1) * 4096 + ((nt0 + 1) * 64 + l) * 8);
                bml  = *(const f16x8*)(mlutF + (i - 1) * 512 + l * 8);
            } else {
                B[0] = *(const f16x8*)(minf + ((nt0 + 0) * 64 + l) * 8);
                B[1] = *(const f16x8*)(minf + ((nt0 + 1) * 64 + l) * 8);
            }
            const float* bo = sp_bout + i * 184;
            float b0v = bo[n0q], b1v = bo[n1q];
            float b2v = (n2q < 184) ? bo[n2q] : 0.f;
            #pragma unroll
            for (int r = 0; r < 4; ++r) {
                uS[0][lqw * 4 + r][n0q] = (f16)(pA0[r] + b0v);
                uS[1][lqw * 4 + r][n0q] = (f16)(pB0[r] + b0v);
                uS[0][lqw * 4 + r][n1q] = (f16)(pA1[r] + b1v);
                uS[1][lqw * 4 + r][n1q] = (f16)(pB1[r] + b1v);
                if (n2q < 184) {
                    uS[0][lqw * 4 + r][n2q] = (f16)(pA2[r] + b2v);
                    uS[1][lqw * 4 + r][n2q] = (f16)(pB2[r] + b2v);
                }
            }
        }
        barrier_lgkm();
        // ---- SPLINE (load-balanced: each 16-thread group does 1 tr + 1 id) ----
        {
            const int g = tid >> 4, rw = tid & 15;
            const int dim = (g < 8) ? g : (g - 8);
            const int trT = (g < 8) ? 0 : 1;   // tile for tr
            const int idT = 1 - trT;           // tile for id
            float y, ldv;
            {
                const float is = 0.08838834764831845f;
                float uw[8], uh[8], udv[7];
                const f16* pr = &uS[trT][rw][dim * 23];
                #pragma unroll
                for (int k = 0; k < 8; ++k) { uw[k] = (float)pr[k] * is; uh[k] = (float)pr[8 + k] * is; }
                #pragma unroll
                for (int k = 0; k < 7; ++k) udv[k] = (float)pr[16 + k];
                float xx = zlu[trT][rw][2 * dim + 1];
                rqs1(xx, uw, uh, udv, y, ldv);
                zO[trT][rw][2 * dim + 1] = y;
                zS[trT][rw][2 * dim + 1] = (f16)y;
                if (trT == 0) ldA += ldv; else ldB += ldv;
            }
            {
                float xx = zlu[idT][rw][2 * dim];
                rqs1_pre(xx, idk + i * 384 + dim * 48, y, ldv);
                zO[idT][rw][2 * dim] = y;
                zS[idT][rw][2 * dim] = (f16)y;
                if (idT == 0) ldA += ldv; else ldB += ldv;
            }
        }
        barrier_lgkm();
    }

    // publish logq partials
    ldS[0][tid >> 4][tid & 15] = ldA;
    ldS[1][tid >> 4][tid & 15] = ldB;

    // ---- MADE stage ----
    {
        const f16* cbA = ctxoutf + (size_t)4 * NHW * 384 + (size_t)hwA * 384;
        const f16* cbB = ctxoutf + (size_t)4 * NHW * 384 + (size_t)hwB * 384;
        {
            f16x8 aA = *(const f16x8*)&zS[0][lr][lqw * 8];
            f16x8 aB = *(const f16x8*)&zS[1][lr][lqw * 8];
            #pragma unroll
            for (int t = 0; t < 2; ++t) {
                int n = (nt0 + t) * 16 + lr;
                float thA = (float)cbA[n];
                float thB = (float)cbB[n];
                f32x4 cA = {thA, thA, thA, thA};
                f32x4 cB = {thB, thB, thB, thB};
                cA = __builtin_amdgcn_mfma_f32_16x16x32_f16(aA, B[t], cA, 0, 0, 0);
                cB = __builtin_amdgcn_mfma_f32_16x16x32_f16(aB, B[t], cB, 0, 0, 0);
                #pragma unroll
                for (int r = 0; r < 4; ++r) {
                    tRA[t][r] = cA[r];
                    tRB[t][r] = cB[r];
                    tS[0][lqw * 4 + r][n] = (f16)fmaxf(cA[r], 0.f);
                    tS[1][lqw * 4 + r][n] = (f16)fmaxf(cB[r], 0.f);
                }
            }
            load8(mW1f, nt0, l, B);
        }
        barrier_lgkm();
        #pragma unroll
        for (int blk = 0; blk < 2; ++blk) {
            {
                f32x4 aA0 = vzero, aA1 = vzero, aB0 = vzero, aB1 = vzero;
                gemm16<136>(tS[0], tS[1], lr, lqw, B, aA0, aA1, aB0, aB1);
                load8(mW2f + blk * 16384, nt0, l, B);
                const float* bb1p = made_bb1 + blk * 128;
                float bi0 = bb1p[(nt0 + 0) * 16 + lr];
                float bi1 = bb1p[(nt0 + 1) * 16 + lr];
                #pragma unroll
                for (int r = 0; r < 4; ++r) {
                    uS[0][lqw * 4 + r][(nt0 + 0) * 16 + lr] = (f16)fmaxf(aA0[r] + bi0, 0.f);
                    uS[0][lqw * 4 + r][(nt0 + 1) * 16 + lr] = (f16)fmaxf(aA1[r] + bi1, 0.f);
                    uS[1][lqw * 4 + r][(nt0 + 0) * 16 + lr] = (f16)fmaxf(aB0[r] + bi0, 0.f);
                    uS[1][lqw * 4 + r][(nt0 + 1) * 16 + lr] = (f16)fmaxf(aB1[r] + bi1, 0.f);
                }
            }
            barrier_lgkm();
            {
                f32x4 aA0 = vzero, aA1 = vzero, aB0 = vzero, aB1 = vzero;
                gemm16<200>(uS[0], uS[1], lr, lqw, B, aA0, aA1, aB0, aB1);
                if (blk == 0) load8(mW1f + 16384, nt0, l, B);
                const float* bb2p = made_bb2 + blk * 128;
                float bi0 = bb2p[(nt0 + 0) * 16 + lr];
                float bi1 = bb2p[(nt0 + 1) * 16 + lr];
                float gA0 = (float)cbA[128 + blk * 128 + (nt0 + 0) * 16 + lr];
                float gA1 = (float)cbA[128 + blk * 128 + (nt0 + 1) * 16 + lr];
                float gB0 = (float)cbB[128 + blk * 128 + (nt0 + 0) * 16 + lr];
                float gB1 = (float)cbB[128 + blk * 128 + (nt0 + 1) * 16 + lr];
                #pragma unroll
                for (int r = 0; r < 4; ++r) {
                    tRA[0][r] += (aA0[r] + bi0) * gA0;
                    tRA[1][r] += (aA1[r] + bi1) * gA1;
                    tRB[0][r] += (aB0[r] + bi0) * gB0;
                    tRB[1][r] += (aB1[r] + bi1) * gB1;
                    if (blk == 0) {
                        tS[0][lqw * 4 + r][(nt0 + 0) * 16 + lr] = (f16)fmaxf(tRA[0][r], 0.f);
                        tS[0][lqw * 4 + r][(nt0 + 1) * 16 + lr] = (f16)fmaxf(tRA[1][r], 0.f);
                        tS[1][lqw * 4 + r][(nt0 + 0) * 16 + lr] = (f16)fmaxf(tRB[0][r], 0.f);
                        tS[1][lqw * 4 + r][(nt0 + 1) * 16 + lr] = (f16)fmaxf(tRB[1][r], 0.f);
                    } else {
                        tS[0][lqw * 4 + r][(nt0 + 0) * 16 + lr] = (f16)tRA[0][r];
                        tS[0][lqw * 4 + r][(nt0 + 1) * 16 + lr] = (f16)tRA[1][r];
                        tS[1][lqw * 4 + r][(nt0 + 0) * 16 + lr] = (f16)tRB[0][r];
                        tS[1][lqw * 4 + r][(nt0 + 1) * 16 + lr] = (f16)tRB[1][r];
                    }
                }
            }
            barrier_lgkm();
        }
        // MADE Wout: waves 0-1 -> tile 0 (nt=w), waves 2-3 -> tile 1 (nt=w-2)
        {
            const int t2 = w >> 1, nt = w & 1;
            f32x4 po = vzero;
            #pragma unroll
            for (int ks = 0; ks < 4; ++ks) {
                f16x8 a = *(const f16x8*)&tS[t2][lr][ks * 32 + lqw * 8];
                f16x8 b = *(const f16x8*)(mWoutf + nt * 2048 + ks * 512 + l * 8);
                po = __builtin_amdgcn_mfma_f32_16x16x32_f16(a, b, po, 0, 0, 0);
            }
            int n = nt * 16 + lr;
            float bias = made_bout[n];
            #pragma unroll
            for (int r = 0; r < 4; ++r)
                uS[t2][lqw * 4 + r][n] = (f16)(po[r] + bias);
        }
    }
    barrier_lgkm();
    // ---- Gaussian head (both tiles) ----
    {
        const int rw = tid >> 4, d = tid & 15;
        #pragma unroll
        for (int t2 = 0; t2 < 2; ++t2) {
            const int gm = m0 + t2 * 16 + rw, hw = gm >> 2, b = gm & 3;
            float ar0 = (float)uS[t2][rw][2 * d];
            float ar1 = (float)uS[t2][rw][2 * d + 1];
            float s = softplusf(ar0) + 0.001f;
            float zn = s * zO[t2][rw][d] + ar1;
            float ls   = ehw[(size_t)hw * 32 + 16 + d];
            float mean = ehw[(size_t)hw * 32 + d];
            float diff = (zn - mean) * fexpf(-ls);
            float g = flogf(s) - ls - 0.5f * diff * diff + ldS[t2][d][rw];
            g += __shfl_xor(g, 1);
            g += __shfl_xor(g, 2);
            g += __shfl_xor(g, 4);
            g += __shfl_xor(g, 8);
            if (d == 0)
                out[(size_t)b * NHW + hw] = g + luc0 - 14.703016531274762f;
        }
    }
}

extern "C" void kernel_launch(void* const* d_in, const int* in_sizes, int n_in,
                              void* d_out, int out_size, void* d_ws, size_t ws_size,
                              hipStream_t stream) {
    (void)in_sizes; (void)n_in; (void)out_size; (void)ws_size;
    const float* x         = (const float*)d_in[0];
    const float* made_W0   = (const float*)d_in[1];
    const float* made_b0   = (const float*)d_in[2];
    const float* made_ctxW = (const float*)d_in[3];
    const float* made_ctxb = (const float*)d_in[4];
    const float* made_bW1  = (const float*)d_in[5];
    const float* made_bb1  = (const float*)d_in[6];
    const float* made_bW2  = (const float*)d_in[7];
    const float* made_bb2  = (const float*)d_in[8];
    const float* made_bCW  = (const float*)d_in[9];
    const float* made_bCb  = (const float*)d_in[10];
    const float* made_Wout = (const float*)d_in[11];
    const float* made_bout = (const float*)d_in[12];
    const float* sp_Win    = (const float*)d_in[13];
    const float* sp_bin    = (const float*)d_in[14];
    const float* sp_bW1    = (const float*)d_in[15];
    const float* sp_bb1    = (const float*)d_in[16];
    const float* sp_bW2    = (const float*)d_in[17];
    const float* sp_bb2    = (const float*)d_in[18];
    const float* sp_bCW    = (const float*)d_in[19];
    const float* sp_bCb    = (const float*)d_in[20];
    const float* sp_Wout   = (const float*)d_in[21];
    const float* sp_bout   = (const float*)d_in[22];
    const float* sp_uw     = (const float*)d_in[23];
    const float* sp_uh     = (const float*)d_in[24];
    const float* sp_ud     = (const float*)d_in[25];
    const float* lu_lower  = (const float*)d_in[26];
    const float* lu_upper  = (const float*)d_in[27];
    const float* lu_udiag  = (const float*)d_in[28];
    const float* lu_bias   = (const float*)d_in[29];
    const int*   lu_perm   = (const int*)d_in[30];
    const float* enc_W1    = (const float*)d_in[31];
    const float* enc_b1    = (const float*)d_in[32];
    const float* enc_W2    = (const float*)d_in[33];
    const float* enc_b2    = (const float*)d_in[34];
    float* out = (float*)d_out;

    float* ws      = (float*)d_ws;
    float* z       = ws;                               // 36864*16
    float* ehw     = z       + (size_t)NROWS * 16;     // 9216*32
    float* cpb     = ehw     + (size_t)NHW * 32;       // 5*384
    float* epb     = cpb     + 5 * 384;                // 160 (pad 192)
    float* idk     = epb     + 192;                    // 4*8*48
    float* beff    = idk     + 1536;                   // 4*128
    float* luc     = beff    + 512;                    // 1 (pad 16)
    f16*   ctxoutf = (f16*)(luc + 16);                 // 5*9216*384 f16
    f16*   fW1f    = ctxoutf + (size_t)5 * NHW * 384;  // 8*16384
    f16*   fW2f    = fW1f    + 8 * 16384;              // 8*16384
    f16*   mW1f    = fW2f    + 8 * 16384;              // 2*16384
    f16*   mW2f    = mW1f    + 2 * 16384;              // 2*16384
    f16*   fWoutf  = mW2f    + 2 * 16384;              // 4*24576
    f16*   mWoutf  = fWoutf  + 4 * 24576;              // 4096
    f16*   weffF   = mWoutf  + 4096;                   // 4*4096
    f16*   mlutF   = weffF   + 4 * 4096;               // 4*512
    f16*   minf    = mlutF   + 4 * 512;                // 4096
    f16*   encW1f  = minf    + 4096;                   // 16384
    f16*   encW2f  = encW1f  + 16384;                  // 4096
    f16*   cfrag   = encW2f  + 4096;                   // 5*49152

    dim3 B(256);
    setup_kernel<<<5124, B, 0, stream>>>(
        x,
        sp_bW1, sp_bW2, made_bW1, made_bW2, sp_Wout, made_Wout, sp_Win, made_W0,
        sp_bCW, made_ctxW, made_bCW, sp_bin, sp_bCb, made_ctxb, made_b0, made_bCb,
        enc_W1, enc_b1, enc_W2, enc_b2,
        sp_uw, sp_uh, sp_ud, lu_lower, lu_upper, lu_udiag, lu_bias, lu_perm,
        z,
        fW1f, fW2f, mW1f, mW2f, fWoutf, mWoutf, minf, cfrag, cpb,
        encW1f, encW2f, epb,
        weffF, mlutF, beff, idk, luc);

    ctx_mfma<<<dim3(576, 3), B, 0, stream>>>(cfrag, cpb, encW1f, encW2f, epb,
                                             ctxoutf, ehw);

    mega_all<<<1152, B, 0, stream>>>(z, ctxoutf, weffF, mlutF, beff, minf,
                                     fW1f, fW2f, mW1f, mW2f, fWoutf, mWoutf,
                                     sp_bb1, sp_bb2, made_bb1, made_bb2,
                                     sp_bout, made_bout,
                                     lu_bias, idk, luc, ehw, out);
}

// Round 25
// 207.732 us; speedup vs baseline: 1.1372x; 1.0084x over previous
//
#include <hip/hip_runtime.h>
#include <math.h>

#define NHW   9216     // 96*96
#define NROWS 36864    // NHW*4

typedef _Float16 f16;
typedef _Float16 f16x8 __attribute__((ext_vector_type(8)));
typedef float    f32x4 __attribute__((ext_vector_type(4)));

// fast transcendentals (hardware v_exp_f32 / v_log_f32 / v_sin / v_cos; rel err ~1e-5)
__device__ __forceinline__ float fexpf(float x) { return __expf(x); }
__device__ __forceinline__ float flogf(float x) { return __logf(x); }
__device__ __forceinline__ float fsinf(float x) { return __sinf(x); }
__device__ __forceinline__ float fcosf(float x) { return __cosf(x); }

__device__ __forceinline__ float softplusf(float x) {
    return fmaxf(x, 0.f) + log1pf(fexpf(-fabsf(x)));
}

// LDS-only barrier: global loads into private VGPRs stay in flight across it.
__device__ __forceinline__ void barrier_lgkm() {
    __builtin_amdgcn_sched_barrier(0);
    asm volatile("s_waitcnt lgkmcnt(0)" ::: "memory");
    __builtin_amdgcn_s_barrier();
    __builtin_amdgcn_sched_barrier(0);
}

// ---------------- knots helper ----------------
__device__ __forceinline__ void knots8(const float* __restrict__ u, float* c, float* w) {
    float mx = u[0];
    #pragma unroll
    for (int k = 1; k < 8; ++k) mx = fmaxf(mx, u[k]);
    float e[8]; float s = 0.f;
    #pragma unroll
    for (int k = 0; k < 8; ++k) { e[k] = fexpf(u[k] - mx); s += e[k]; }
    float inv = 1.f / s;
    c[0] = -3.f;
    float cum = 0.f;
    #pragma unroll
    for (int k = 0; k < 8; ++k) {
        float v = 0.001f + 0.992f * e[k] * inv;
        cum += v;
        c[k + 1] = cum * 6.f - 3.f;
    }
    c[8] = 3.f;
    #pragma unroll
    for (int k = 0; k < 8; ++k) w[k] = c[k + 1] - c[k];
}

// ---------------- merged setup kernel: snorm | pack | prep ----------------
// blocks [0,2304): snorm tiles; [2304,5049): pack (flat 702496 elems);
// [5049,5123): prep fragment work (each recomputes Mlu in LDS); block 5123: idk+luc.
__global__ __launch_bounds__(256) void setup_kernel(
    const float* __restrict__ x,
    const float* __restrict__ sp_bW1, const float* __restrict__ sp_bW2,
    const float* __restrict__ made_bW1, const float* __restrict__ made_bW2,
    const float* __restrict__ sp_Wout, const float* __restrict__ made_Wout,
    const float* __restrict__ sp_Win, const float* __restrict__ made_W0,
    const float* __restrict__ sp_bCW, const float* __restrict__ made_ctxW,
    const float* __restrict__ made_bCW,
    const float* __restrict__ sp_bin, const float* __restrict__ sp_bCb,
    const float* __restrict__ made_ctxb, const float* __restrict__ made_b0,
    const float* __restrict__ made_bCb,
    const float* __restrict__ enc_W1, const float* __restrict__ enc_b1,
    const float* __restrict__ enc_W2, const float* __restrict__ enc_b2,
    const float* __restrict__ sp_uw, const float* __restrict__ sp_uh,
    const float* __restrict__ sp_ud,
    const float* __restrict__ lu_lower, const float* __restrict__ lu_upper,
    const float* __restrict__ lu_udiag, const float* __restrict__ lu_bias,
    const int*   __restrict__ lu_perm,
    float* __restrict__ z,
    f16* __restrict__ fW1f, f16* __restrict__ fW2f,
    f16* __restrict__ mW1f, f16* __restrict__ mW2f,
    f16* __restrict__ fWoutf, f16* __restrict__ mWoutf,
    f16* __restrict__ minf,
    f16* __restrict__ cfrag, float* __restrict__ cpb,
    f16* __restrict__ encW1f, f16* __restrict__ encW2f, float* __restrict__ epb,
    f16* __restrict__ weffF, f16* __restrict__ mlutF,
    float* __restrict__ beff, float* __restrict__ idk, float* __restrict__ luc)
{
    __shared__ float sS[33][34];
    __shared__ float sMlu[4][16][16];
    const int bid = blockIdx.x;
    const int t = threadIdx.x;

    if (bid < 2304) {
        const int bs   = bid / 36;
        const int tile = bid % 36;
        const int ti = tile / 6, tj = tile % 6;
        const int i0 = ti * 16, j0 = tj * 16;
        const int b = bs >> 4, s = bs & 15;
        const float* xb = x + (size_t)(bs * 3) * 36864;
        for (int e = t; e < 33 * 33; e += 256) {
            int row = e / 33, col = e % 33;
            int hh = 2 * i0 - 1 + row, ww = 2 * j0 - 1 + col;
            float acc = 0.f;
            if (hh >= 0 && hh < 192 && ww >= 0 && ww < 192) {
                #pragma unroll
                for (int c = 0; c < 3; ++c) {
                    float v = xb[c * 36864 + hh * 192 + ww];
                    acc += v * v;
                }
            }
            sS[row][col] = acc;
        }
        __syncthreads();
        const int oi = t >> 4, oj = t & 15;
        float sum = 0.f;
        #pragma unroll
        for (int dr = 0; dr < 3; ++dr)
            #pragma unroll
            for (int dc = 0; dc < 3; ++dc)
                sum += sS[2 * oi + dr][2 * oj + dc];
        const int i = i0 + oi, j = j0 + oj;
        z[((size_t)(i * 96 + j) * 4 + b) * 16 + s] = sqrtf(sum);
        return;
    }

    if (bid < 5049) {
        int idx = (bid - 2304) * 256 + t;
        if (idx < 131072) {
            int e = idx;
            int mtx = e >> 14, f = e & 16383;
            int nt = f >> 11, ks = (f >> 9) & 3, l = (f >> 3) & 63, j = f & 7;
            int n = nt * 16 + (l & 15), k = ks * 32 + ((l >> 4) & 3) * 8 + j;
            fW1f[e] = (f16)sp_bW1[mtx * 16384 + n * 128 + k];
            return;
        }
        idx -= 131072;
        if (idx < 131072) {
            int e = idx;
            int mtx = e >> 14, f = e & 16383;
            int nt = f >> 11, ks = (f >> 9) & 3, l = (f >> 3) & 63, j = f & 7;
            int n = nt * 16 + (l & 15), k = ks * 32 + ((l >> 4) & 3) * 8 + j;
            fW2f[e] = (f16)sp_bW2[mtx * 16384 + n * 128 + k];
            return;
        }
        idx -= 131072;
        if (idx < 32768) {
            int e = idx;
            int mtx = e >> 14, f = e & 16383;
            int nt = f >> 11, ks = (f >> 9) & 3, l = (f >> 3) & 63, j = f & 7;
            int n = nt * 16 + (l & 15), k = ks * 32 + ((l >> 4) & 3) * 8 + j;
            mW1f[e] = ((n % 15) >= (k % 15)) ? (f16)made_bW1[mtx * 16384 + n * 128 + k] : (f16)0.f;
            return;
        }
        idx -= 32768;
        if (idx < 32768) {
            int e = idx;
            int mtx = e >> 14, f = e & 16383;
            int nt = f >> 11, ks = (f >> 9) & 3, l = (f >> 3) & 63, j = f & 7;
            int n = nt * 16 + (l & 15), k = ks * 32 + ((l >> 4) & 3) * 8 + j;
            mW2f[e] = ((n % 15) >= (k % 15)) ? (f16)made_bW2[mtx * 16384 + n * 128 + k] : (f16)0.f;
            return;
        }
        idx -= 32768;
        if (idx < 98304) {
            int e = idx;
            int s = e / 24576, f = e % 24576;
            int nt = f >> 11, ks = (f >> 9) & 3, l = (f >> 3) & 63, j = f & 7;
            int n = nt * 16 + (l & 15), k = ks * 32 + ((l >> 4) & 3) * 8 + j;
            fWoutf[e] = (n < 184) ? (f16)sp_Wout[s * 23552 + n * 128 + k] : (f16)0.f;
            return;
        }
        idx -= 98304;
        if (idx < 4096) {
            int f = idx;
            int nt = f >> 11, ks = (f >> 9) & 3, l = (f >> 3) & 63, j = f & 7;
            int n = nt * 16 + (l & 15), k = ks * 32 + ((l >> 4) & 3) * 8 + j;
            mWoutf[idx] = (((n & 15) > (k % 15)) && n < 32) ? (f16)made_Wout[n * 128 + k] : (f16)0.f;
            return;
        }
        idx -= 4096;
        if (idx < 4096) {
            int f = idx;
            int nt = f >> 9, l = (f >> 3) & 63, j = f & 7;
            int n = nt * 16 + (l & 15), k = ((l >> 4) & 3) * 8 + j;
            minf[idx] = (k < 16 && (n % 15) >= k) ? (f16)made_W0[n * 16 + k] : (f16)0.f;
            return;
        }
        idx -= 4096;
        if (idx < 245760) {
            int e = idx;
            int s = e / 49152, f = e % 49152;
            int nt = f >> 11, ks = (f >> 9) & 3, l = (f >> 3) & 63, j = f & 7;
            int n = nt * 16 + (l & 15), k = ks * 32 + ((l >> 4) & 3) * 8 + j;
            float v;
            if (s < 4) {
                if (n < 128)      v = sp_Win[s * 17408 + n * 136 + 8 + k];
                else if (n < 256) v = sp_bCW[(size_t)(s * 2 + 0) * 16384 + (n - 128) * 128 + k];
                else              v = sp_bCW[(size_t)(s * 2 + 1) * 16384 + (n - 256) * 128 + k];
            } else {
                if (n < 128)      v = made_ctxW[n * 128 + k];
                else if (n < 256) v = made_bCW[(n - 128) * 128 + k];
                else              v = made_bCW[16384 + (n - 256) * 128 + k];
            }
            cfrag[e] = (f16)v;
            return;
        }
        idx -= 245760;
        if (idx < 1920) {
            int e = idx;
            int s = e / 384, n = e % 384;
            float v;
            if (s < 4) {
                if (n < 128)      v = sp_bin[s * 128 + n];
                else if (n < 256) v = sp_bCb[(s * 2 + 0) * 128 + (n - 128)];
                else              v = sp_bCb[(s * 2 + 1) * 128 + (n - 256)];
            } else {
                if (n < 128)      v = made_ctxb[n] + made_b0[n];
                else if (n < 256) v = made_bCb[n - 128];
                else              v = made_bCb[128 + (n - 256)];
            }
            cpb[e] = v;
            return;
        }
        idx -= 1920;
        if (idx < 16384) {
            int f = idx;
            int nt = f >> 11, ks = (f >> 9) & 3, l = (f >> 3) & 63, j = f & 7;
            int n = nt * 16 + (l & 15), k = ks * 32 + ((l >> 4) & 3) * 8 + j;
            encW1f[idx] = (f16)enc_W1[n * 128 + k];
            return;
        }
        idx -= 16384;
        if (idx < 4096) {
            int f = idx;
            int nt = f >> 11, ks = (f >> 9) & 3, l = (f >> 3) & 63, j = f & 7;
            int n = nt * 16 + (l & 15), k = ks * 32 + ((l >> 4) & 3) * 8 + j;
            encW2f[idx] = (n < 32) ? (f16)enc_W2[n * 128 + k] : (f16)0.f;
            return;
        }
        idx -= 4096;
        if (idx < 160) {
            epb[idx] = (idx < 128) ? enc_b1[idx] : enc_b2[idx - 128];
        }
        return;
    }

    if (bid == 5123) {
        if (t < 32) {
            int s = t >> 3, dim = t & 7;
            float* o = idk + (s * 8 + dim) * 48;
            float c[9], w[8];
            knots8(sp_uw + s * 64 + dim * 8, c, w);
            #pragma unroll
            for (int k = 0; k < 9; ++k) o[k] = c[k];
            #pragma unroll
            for (int k = 0; k < 8; ++k) o[9 + k] = w[k];
            knots8(sp_uh + s * 64 + dim * 8, c, w);
            #pragma unroll
            for (int k = 0; k < 9; ++k) o[17 + k] = c[k];
            #pragma unroll
            for (int k = 0; k < 8; ++k) o[26 + k] = w[k];
            o[34] = 1.f; o[42] = 1.f;
            #pragma unroll
            for (int k = 0; k < 7; ++k) o[35 + k] = 0.001f + softplusf(sp_ud[s * 56 + dim * 7 + k]);
        } else if (t == 32) {
            float c0 = 0.f;
            for (int k = 0; k < 64; ++k)
                c0 += flogf(softplusf(lu_udiag[k]) + 0.001f);
            luc[0] = c0;
        }
        return;
    }

    // ---- prep fragment blocks [5049,5123) ----
    {
        if (t < 64) {
            int s = t >> 4, d = t & 15;
            const float* L  = lu_lower + s * 256;
            const float* U  = lu_upper + s * 256;
            const float* ud = lu_udiag + s * 16;
            const int*   pm = lu_perm + s * 16;
            for (int c = 0; c < 16; ++c) {
                float m = 0.f;
                if (c > d)       m += U[d * 16 + c];
                else if (c == d) m += softplusf(ud[d]) + 0.001f;
                for (int e = 0; e < d && e <= c; ++e) {
                    float u = (c > e) ? U[e * 16 + c] : (softplusf(ud[e]) + 0.001f);
                    m += L[d * 16 + e] * u;
                }
                sMlu[s][d][pm[c]] = m;
            }
        }
        __syncthreads();
        int idx = (bid - 5049) * 256 + t;
        if (idx < 16384) {
            int e = idx;
            int s = e >> 12, f = e & 4095;
            int nt = f >> 9, l = (f >> 3) & 63, j = f & 7;
            int n = nt * 16 + (l & 15), k = ((l >> 4) & 3) * 8 + j;
            float v = 0.f;
            if (k < 16) {
                #pragma unroll
                for (int p = 0; p < 8; ++p)
                    v += sMlu[s][2 * p][k] * sp_Win[s * 17408 + n * 136 + p];
            }
            weffF[e] = (f16)v;
        } else if (idx < 18432) {
            int e = idx - 16384;
            int s = e >> 9, f = e & 511;
            int l = f >> 3, j = f & 7;
            int n = l & 15, k = (l >> 4) * 8 + j;
            mlutF[e] = (k < 16) ? (f16)sMlu[s][n][k] : (f16)0.f;
        } else if (idx < 18944) {
            int e = idx - 18432;
            int s = e >> 7, n = e & 127;
            float v = 0.f;
            #pragma unroll
            for (int p = 0; p < 8; ++p)
                v += lu_bias[s * 16 + 2 * p] * sp_Win[s * 17408 + n * 136 + p];
            beff[e] = v;
        }
        return;
    }
}

// ---------------- ctx-chain MFMA: 2 slices per block ----------------
__global__ __launch_bounds__(256) void ctx_mfma(
    const f16* __restrict__ cfrag,
    const float* __restrict__ cpb,
    const f16* __restrict__ encW1f, const f16* __restrict__ encW2f,
    const float* __restrict__ epb,
    f16* __restrict__ ctxoutf, float* __restrict__ ehw)
{
    __shared__ alignas(16) f16 cS[16][136];
    __shared__ alignas(16) f16 hS[16][136];
    const int tid = threadIdx.x, w = tid >> 6, l = tid & 63;
    const int m0 = blockIdx.x * 16;
    const int sy = blockIdx.y;
    const int lr = l & 15, lq = l >> 4;
    #pragma unroll
    for (int it = 0; it < 2; ++it) {
        int e = tid + it * 256;
        int r = e >> 5, c4 = (e & 31) * 4;
        int hw = m0 + r;
        int ii = hw / 96, jj = hw % 96;
        #pragma unroll
        for (int q = 0; q < 4; ++q) {
            int c = c4 + q;
            int pos = (c < 64) ? ii : jj;
            int cc = c & 63;
            int k = cc >> 1;
            float invf = exp2f((float)k * -0.4152410118609203f);  // 10000^(-k/32)
            float v = (float)pos * invf;
            cS[r][c] = (f16)((cc & 1) ? fcosf(v) : fsinf(v));
        }
    }
    __syncthreads();
    const f32x4 vzero = {0.f, 0.f, 0.f, 0.f};
    #pragma unroll
    for (int sub = 0; sub < 2; ++sub) {
        const int s = sy * 2 + sub;
        if (s < 5) {
            f32x4 acc[6];
            #pragma unroll
            for (int q = 0; q < 6; ++q) acc[q] = vzero;
            const f16* wb = cfrag + (size_t)s * 49152;
            #pragma unroll
            for (int ks = 0; ks < 4; ++ks) {
                f16x8 a = *(const f16x8*)&cS[lr][ks * 32 + lq * 8];
                #pragma unroll
                for (int q = 0; q < 6; ++q) {
                    int g = w * 6 + q;
                    f16x8 b = *(const f16x8*)(wb + (size_t)((g * 4 + ks) * 64 + l) * 8);
                    acc[q] = __builtin_amdgcn_mfma_f32_16x16x32_f16(a, b, acc[q], 0, 0, 0);
                }
            }
            #pragma unroll
            for (int q = 0; q < 6; ++q) {
                int g = w * 6 + q, n = g * 16 + lr;
                float bias = cpb[s * 384 + n];
                #pragma unroll
                for (int r = 0; r < 4; ++r) {
                    float val = acc[q][r] + bias;
                    if (n >= 128) val = 1.f / (1.f + fexpf(-val));
                    ctxoutf[(size_t)s * NHW * 384 + (size_t)(m0 + lq * 4 + r) * 384 + n] = (f16)val;
                }
            }
        } else {
            f32x4 acc0 = vzero, acc1 = vzero;
            #pragma unroll
            for (int ks = 0; ks < 4; ++ks) {
                f16x8 a = *(const f16x8*)&cS[lr][ks * 32 + lq * 8];
                f16x8 b0 = *(const f16x8*)(encW1f + (((w * 2 + 0) * 4 + ks) * 64 + l) * 8);
                f16x8 b1 = *(const f16x8*)(encW1f + (((w * 2 + 1) * 4 + ks) * 64 + l) * 8);
                acc0 = __builtin_amdgcn_mfma_f32_16x16x32_f16(a, b0, acc0, 0, 0, 0);
                acc1 = __builtin_amdgcn_mfma_f32_16x16x32_f16(a, b1, acc1, 0, 0, 0);
            }
            {
                int n0 = (w * 2 + 0) * 16 + lr, n1 = (w * 2 + 1) * 16 + lr;
                float bi0 = epb[n0], bi1 = epb[n1];
                #pragma unroll
                for (int r = 0; r < 4; ++r) {
                    float v0 = acc0[r] + bi0, v1 = acc1[r] + bi1;
                    hS[lq * 4 + r][n0] = (f16)(v0 / (1.f + fexpf(-v0)));
                    hS[lq * 4 + r][n1] = (f16)(v1 / (1.f + fexpf(-v1)));
                }
            }
            __syncthreads();
            if (w < 2) {
                f32x4 po = vzero;
                #pragma unroll
                for (int ks = 0; ks < 4; ++ks) {
                    f16x8 a = *(const f16x8*)&hS[lr][ks * 32 + lq * 8];
                    f16x8 b = *(const f16x8*)(encW2f + ((w * 4 + ks) * 64 + l) * 8);
                    po = __builtin_amdgcn_mfma_f32_16x16x32_f16(a, b, po, 0, 0, 0);
                }
                int n = w * 16 + lr;
                float bias = epb[128 + n];
                #pragma unroll
                for (int r = 0; r < 4; ++r)
                    ehw[(size_t)(m0 + lq * 4 + r) * 32 + n] = po[r] + bias;
            }
        }
    }
}

// ---------------- rational-quadratic spline ----------------
__device__ __forceinline__ void rqs_core(float x, const float* cw, const float* wd,
                                         const float* ch, const float* hg, const float* dd,
                                         float& y, float& ld) {
    bool inside = (x >= -3.f) && (x <= 3.f);
    float xc = fminf(fmaxf(x, -3.f), 3.f);
    float cwk = cw[0], wk = wd[0], chk = ch[0], hk = hg[0], d0 = dd[0], d1 = dd[1];
    #pragma unroll
    for (int k = 1; k < 8; ++k) {
        if (xc >= cw[k]) { cwk = cw[k]; wk = wd[k]; chk = ch[k]; hk = hg[k]; d0 = dd[k]; d1 = dd[k + 1]; }
    }
    float dl = hk / wk;
    float th = (xc - cwk) / wk;
    float t1 = th * (1.f - th);
    float den = dl + (d0 + d1 - 2.f * dl) * t1;
    float yy = chk + hk * (dl * th * th + d0 * t1) / den;
    float om = 1.f - th;
    float dnum = dl * dl * (d1 * th * th + 2.f * dl * t1 + d0 * om * om);
    float lld = flogf(dnum) - 2.f * flogf(den);
    y  = inside ? yy : x;
    ld = inside ? lld : 0.f;
}

__device__ __forceinline__ void rqs1(float x,
                                     const float* __restrict__ uw,
                                     const float* __restrict__ uh,
                                     const float* __restrict__ ud,
                                     float& y, float& ld) {
    float cw[9], wd[8], ch[9], hg[8], dd[9];
    knots8(uw, cw, wd);
    knots8(uh, ch, hg);
    dd[0] = 1.f; dd[8] = 1.f;
    #pragma unroll
    for (int k = 0; k < 7; ++k) dd[k + 1] = 0.001f + softplusf(ud[k]);
    rqs_core(x, cw, wd, ch, hg, dd, y, ld);
}

__device__ __forceinline__ void rqs1_pre(float x, const float* __restrict__ kn,
                                         float& y, float& ld) {
    float cw[9], wd[8], ch[9], hg[8], dd[9];
    #pragma unroll
    for (int k = 0; k < 9; ++k) cw[k] = kn[k];
    #pragma unroll
    for (int k = 0; k < 8; ++k) wd[k] = kn[9 + k];
    #pragma unroll
    for (int k = 0; k < 9; ++k) ch[k] = kn[17 + k];
    #pragma unroll
    for (int k = 0; k < 8; ++k) hg[k] = kn[26 + k];
    #pragma unroll
    for (int k = 0; k < 9; ++k) dd[k] = kn[34 + k];
    rqs_core(x, cw, wd, ch, hg, dd, y, ld);
}

// ---------------- prefetch helpers ----------------
__device__ __forceinline__ void load8(const f16* __restrict__ w, int nt0, int l,
                                      f16x8 B[8]) {
    #pragma unroll
    for (int q = 0; q < 2; ++q)
        #pragma unroll
        for (int ks = 0; ks < 4; ++ks)
            B[q * 4 + ks] = *(const f16x8*)(w + (nt0 + q) * 2048 + ks * 512 + l * 8);
}

// two-tile GEMM: shared B-frags, A-frags from both tiles' LDS (stride-templated)
template<int S>
__device__ __forceinline__ void gemm16(const f16 (*__restrict__ SA)[S],
                                       const f16 (*__restrict__ SB)[S],
                                       int lr, int lqw, const f16x8 B[8],
                                       f32x4& aA0, f32x4& aA1, f32x4& aB0, f32x4& aB1) {
    __builtin_amdgcn_s_setprio(1);
    #pragma unroll
    for (int ks = 0; ks < 4; ++ks) {
        f16x8 aA = *(const f16x8*)&SA[lr][ks * 32 + lqw * 8];
        f16x8 aB = *(const f16x8*)&SB[lr][ks * 32 + lqw * 8];
        aA0 = __builtin_amdgcn_mfma_f32_16x16x32_f16(aA, B[ks], aA0, 0, 0, 0);
        aB0 = __builtin_amdgcn_mfma_f32_16x16x32_f16(aB, B[ks], aB0, 0, 0, 0);
        aA1 = __builtin_amdgcn_mfma_f32_16x16x32_f16(aA, B[4 + ks], aA1, 0, 0, 0);
        aB1 = __builtin_amdgcn_mfma_f32_16x16x32_f16(aB, B[4 + ks], aB1, 0, 0, 0);
    }
    __builtin_amdgcn_s_setprio(0);
}

// ---------------- merged pipeline: TWO 16-row tiles per block ----------------
// Union buffer stride 200: row stride 400 B = 25*16 keeps f16x8 LDS reads
// 16B-aligned (ds_read_b128); r23's stride 196 broke alignment and cost 17%.
__global__ __launch_bounds__(256) void mega_all(
    const float* __restrict__ zg,
    const f16*  __restrict__ ctxoutf,   // [5][9216][384]
    const f16*  __restrict__ weffF,     // [4][4096]
    const f16*  __restrict__ mlutF,     // [4][512]
    const float* __restrict__ beffv,    // [4][128]
    const f16*  __restrict__ minf,      // [4096]
    const f16*  __restrict__ fW1f,      // [4][2][16384]
    const f16*  __restrict__ fW2f,
    const f16*  __restrict__ mW1f,      // [2][16384]
    const f16*  __restrict__ mW2f,
    const f16*  __restrict__ fWoutf,    // [4][24576]
    const f16*  __restrict__ mWoutf,    // [4096]
    const float* __restrict__ sp_bb1,   // [4][2][128]
    const float* __restrict__ sp_bb2,
    const float* __restrict__ made_bb1, // [2][128]
    const float* __restrict__ made_bb2,
    const float* __restrict__ sp_bout,  // [4][184]
    const float* __restrict__ made_bout,// [32]
    const float* __restrict__ lu_bias,  // [4][16]
    const float* __restrict__ idk,      // [4][8][48]
    const float* __restrict__ luc,      // [1]
    const float* __restrict__ ehw,      // [9216][32]
    float* __restrict__ out)            // [4][9216]
{
    __shared__ alignas(16) f16 tS[2][16][136];
    __shared__ alignas(16) f16 uS[2][16][200];   // union: residual hidden (cols<128) / WOUT out (cols<196)
    __shared__ alignas(16) f16 zS[2][16][32];
    __shared__ float zlu[2][16][17];
    __shared__ float zO[2][16][17];
    __shared__ float ldS[2][16][17];
    const int tid = threadIdx.x;
    const int w   = tid >> 6;
    const int l   = tid & 63;
    const int lr  = l & 15;
    const int lqw = l >> 4;
    const int m0  = blockIdx.x * 32;
    const int hwA = (m0 >> 2) + lqw;
    const int hwB = hwA + 4;
    const int nt0 = w * 2;
    const f32x4 vzero = {0.f, 0.f, 0.f, 0.f};

    #pragma unroll
    for (int it = 0; it < 2; ++it) {
        int e = tid + it * 256;
        int rr = e >> 4, d2 = e & 15;
        int t2 = rr >> 4, r2 = rr & 15;
        zS[t2][r2][d2] = (f16)zg[(size_t)(m0 + rr) * 16 + d2];
        zS[t2][r2][16 + d2] = (f16)0.f;
    }
    float luc0 = luc[0];
    float ldA = 0.f, ldB = 0.f;

    f16x8 B[8];
    f16x8 bml;
    B[0] = *(const f16x8*)(weffF + 3 * 4096 + ((nt0 + 0) * 64 + l) * 8);
    B[1] = *(const f16x8*)(weffF + 3 * 4096 + ((nt0 + 1) * 64 + l) * 8);
    bml  = *(const f16x8*)(mlutF + 3 * 512 + l * 8);
    barrier_lgkm();

    const int n0q = (w + 0) * 16 + lr, n1q = (w + 4) * 16 + lr, n2q = (w + 8) * 16 + lr;

    float tRA[2][4], tRB[2][4];

    for (int i = 3; i >= 0; --i) {
        const f16* cbA = ctxoutf + (size_t)i * NHW * 384 + (size_t)hwA * 384;
        const f16* cbB = ctxoutf + (size_t)i * NHW * 384 + (size_t)hwB * 384;
        // ---- IN ----
        {
            f16x8 aA = *(const f16x8*)&zS[0][lr][lqw * 8];
            f16x8 aB = *(const f16x8*)&zS[1][lr][lqw * 8];
            if (w < 2) {
                float bl = lu_bias[i * 16 + lr];
                f32x4 c = {bl, bl, bl, bl};
                c = __builtin_amdgcn_mfma_f32_16x16x32_f16(w == 0 ? aA : aB, bml, c, 0, 0, 0);
                #pragma unroll
                for (int r = 0; r < 4; ++r)
                    zlu[w][lqw * 4 + r][lr] = c[r];
            }
            #pragma unroll
            for (int t = 0; t < 2; ++t) {
                int n = (nt0 + t) * 16 + lr;
                float bf = beffv[i * 128 + n];
                float ciA = (float)cbA[n] + bf;
                float ciB = (float)cbB[n] + bf;
                f32x4 cA = {ciA, ciA, ciA, ciA};
                f32x4 cB = {ciB, ciB, ciB, ciB};
                cA = __builtin_amdgcn_mfma_f32_16x16x32_f16(aA, B[t], cA, 0, 0, 0);
                cB = __builtin_amdgcn_mfma_f32_16x16x32_f16(aB, B[t], cB, 0, 0, 0);
                #pragma unroll
                for (int r = 0; r < 4; ++r) {
                    tRA[t][r] = cA[r];
                    tRB[t][r] = cB[r];
                    tS[0][lqw * 4 + r][n] = (f16)fmaxf(cA[r], 0.f);
                    tS[1][lqw * 4 + r][n] = (f16)fmaxf(cB[r], 0.f);
                }
            }
            load8(fW1f + (size_t)i * 32768, nt0, l, B);
        }
        barrier_lgkm();
        // ---- residual blocks ----
        #pragma unroll
        for (int blk = 0; blk < 2; ++blk) {
            // W1
            {
                f32x4 aA0 = vzero, aA1 = vzero, aB0 = vzero, aB1 = vzero;
                gemm16<136>(tS[0], tS[1], lr, lqw, B, aA0, aA1, aB0, aB1);
                load8(fW2f + (size_t)i * 32768 + blk * 16384, nt0, l, B);
                const float* bb1p = sp_bb1 + i * 256 + blk * 128;
                float bi0 = bb1p[(nt0 + 0) * 16 + lr];
                float bi1 = bb1p[(nt0 + 1) * 16 + lr];
                #pragma unroll
                for (int r = 0; r < 4; ++r) {
                    uS[0][lqw * 4 + r][(nt0 + 0) * 16 + lr] = (f16)fmaxf(aA0[r] + bi0, 0.f);
                    uS[0][lqw * 4 + r][(nt0 + 1) * 16 + lr] = (f16)fmaxf(aA1[r] + bi1, 0.f);
                    uS[1][lqw * 4 + r][(nt0 + 0) * 16 + lr] = (f16)fmaxf(aB0[r] + bi0, 0.f);
                    uS[1][lqw * 4 + r][(nt0 + 1) * 16 + lr] = (f16)fmaxf(aB1[r] + bi1, 0.f);
                }
            }
            barrier_lgkm();
            // W2
            {
                f32x4 aA0 = vzero, aA1 = vzero, aB0 = vzero, aB1 = vzero;
                gemm16<200>(uS[0], uS[1], lr, lqw, B, aA0, aA1, aB0, aB1);
                if (blk == 0) load8(fW1f + (size_t)i * 32768 + 16384, nt0, l, B);
                else {
                    const f16* wo = fWoutf + (size_t)i * 24576;
                    #pragma unroll
                    for (int t2 = 0; t2 < 2; ++t2)
                        #pragma unroll
                        for (int ks = 0; ks < 4; ++ks)
                            B[t2 * 4 + ks] = *(const f16x8*)(wo + (w + t2 * 4) * 2048 + ks * 512 + l * 8);
                }
                const float* bb2p = sp_bb2 + i * 256 + blk * 128;
                float bi0 = bb2p[(nt0 + 0) * 16 + lr];
                float bi1 = bb2p[(nt0 + 1) * 16 + lr];
                float gA0 = (float)cbA[128 + blk * 128 + (nt0 + 0) * 16 + lr];
                float gA1 = (float)cbA[128 + blk * 128 + (nt0 + 1) * 16 + lr];
                float gB0 = (float)cbB[128 + blk * 128 + (nt0 + 0) * 16 + lr];
                float gB1 = (float)cbB[128 + blk * 128 + (nt0 + 1) * 16 + lr];
                #pragma unroll
                for (int r = 0; r < 4; ++r) {
                    tRA[0][r] += (aA0[r] + bi0) * gA0;
                    tRA[1][r] += (aA1[r] + bi1) * gA1;
                    tRB[0][r] += (aB0[r] + bi0) * gB0;
                    tRB[1][r] += (aB1[r] + bi1) * gB1;
                    if (blk == 0) {
                        tS[0][lqw * 4 + r][(nt0 + 0) * 16 + lr] = (f16)fmaxf(tRA[0][r], 0.f);
                        tS[0][lqw * 4 + r][(nt0 + 1) * 16 + lr] = (f16)fmaxf(tRA[1][r], 0.f);
                        tS[1][lqw * 4 + r][(nt0 + 0) * 16 + lr] = (f16)fmaxf(tRB[0][r], 0.f);
                        tS[1][lqw * 4 + r][(nt0 + 1) * 16 + lr] = (f16)fmaxf(tRB[1][r], 0.f);
                    } else {
                        tS[0][lqw * 4 + r][(nt0 + 0) * 16 + lr] = (f16)tRA[0][r];
                        tS[0][lqw * 4 + r][(nt0 + 1) * 16 + lr] = (f16)tRA[1][r];
                        tS[1][lqw * 4 + r][(nt0 + 0) * 16 + lr] = (f16)tRB[0][r];
                        tS[1][lqw * 4 + r][(nt0 + 1) * 16 + lr] = (f16)tRB[1][r];
                    }
                }
            }
            barrier_lgkm();
        }
        // ---- WOUT -> uS (union; both tiles; B holds nt w, w+4) ----
        {
            f32x4 pA0 = vzero, pA1 = vzero, pA2 = vzero;
            f32x4 pB0 = vzero, pB1 = vzero, pB2 = vzero;
            const f16* wo = fWoutf + (size_t)i * 24576;
            __builtin_amdgcn_s_setprio(1);
            #pragma unroll
            for (int ks = 0; ks < 4; ++ks) {
                f16x8 aA = *(const f16x8*)&tS[0][lr][ks * 32 + lqw * 8];
                f16x8 aB = *(const f16x8*)&tS[1][lr][ks * 32 + lqw * 8];
                pA0 = __builtin_amdgcn_mfma_f32_16x16x32_f16(aA, B[ks], pA0, 0, 0, 0);
                pB0 = __builtin_amdgcn_mfma_f32_16x16x32_f16(aB, B[ks], pB0, 0, 0, 0);
                pA1 = __builtin_amdgcn_mfma_f32_16x16x32_f16(aA, B[4 + ks], pA1, 0, 0, 0);
                pB1 = __builtin_amdgcn_mfma_f32_16x16x32_f16(aB, B[4 + ks], pB1, 0, 0, 0);
                f16x8 b2 = *(const f16x8*)(wo + (w + 8) * 2048 + ks * 512 + l * 8);
                pA2 = __builtin_amdgcn_mfma_f32_16x16x32_f16(aA, b2, pA2, 0, 0, 0);
                pB2 = __builtin_amdgcn_mfma_f32_16x16x32_f16(aB, b2, pB2, 0, 0, 0);
            }
            __builtin_amdgcn_s_setprio(0);
            if (i > 0) {
                B[0] = *(const f16x8*)(weffF + (i - 1) * 4096 + ((nt0 + 0) * 64 + l) * 8);
                B[1] = *(const f16x8*)(weffF + (i - 1) * 4096 + ((nt0 + 1) * 64 + l) * 8);
                bml  = *(const f16x8*)(mlutF + (i - 1) * 512 + l * 8);
            } else {
                B[0] = *(const f16x8*)(minf + ((nt0 + 0) * 64 + l) * 8);
                B[1] = *(const f16x8*)(minf + ((nt0 + 1) * 64 + l) * 8);
            }
            const float* bo = sp_bout + i * 184;
            float b0v = bo[n0q], b1v = bo[n1q];
            float b2v = (n2q < 184) ? bo[n2q] : 0.f;
            #pragma unroll
            for (int r = 0; r < 4; ++r) {
                uS[0][lqw * 4 + r][n0q] = (f16)(pA0[r] + b0v);
                uS[1][lqw * 4 + r][n0q] = (f16)(pB0[r] + b0v);
                uS[0][lqw * 4 + r][n1q] = (f16)(pA1[r] + b1v);
                uS[1][lqw * 4 + r][n1q] = (f16)(pB1[r] + b1v);
                if (n2q < 184) {
                    uS[0][lqw * 4 + r][n2q] = (f16)(pA2[r] + b2v);
                    uS[1][lqw * 4 + r][n2q] = (f16)(pB2[r] + b2v);
                }
            }
        }
        barrier_lgkm();
        // ---- SPLINE (load-balanced: each 16-thread group does 1 tr + 1 id) ----
        {
            const int g = tid >> 4, rw = tid & 15;
            const int dim = (g < 8) ? g : (g - 8);
            const int trT = (g < 8) ? 0 : 1;   // tile for tr
            const int idT = 1 - trT;           // tile for id
            float y, ldv;
            {
                const float is = 0.08838834764831845f;
                float uw[8], uh[8], udv[7];
                const f16* pr = &uS[trT][rw][dim * 23];
                #pragma unroll
                for (int k = 0; k < 8; ++k) { uw[k] = (float)pr[k] * is; uh[k] = (float)pr[8 + k] * is; }
                #pragma unroll
                for (int k = 0; k < 7; ++k) udv[k] = (float)pr[16 + k];
                float xx = zlu[trT][rw][2 * dim + 1];
                rqs1(xx, uw, uh, udv, y, ldv);
                zO[trT][rw][2 * dim + 1] = y;
                zS[trT][rw][2 * dim + 1] = (f16)y;
                if (trT == 0) ldA += ldv; else ldB += ldv;
            }
            {
                float xx = zlu[idT][rw][2 * dim];
                rqs1_pre(xx, idk + i * 384 + dim * 48, y, ldv);
                zO[idT][rw][2 * dim] = y;
                zS[idT][rw][2 * dim] = (f16)y;
                if (idT == 0) ldA += ldv; else ldB += ldv;
            }
        }
        barrier_lgkm();
    }

    // publish logq partials
    ldS[0][tid >> 4][tid & 15] = ldA;
    ldS[1][tid >> 4][tid & 15] = ldB;

    // ---- MADE stage ----
    {
        const f16* cbA = ctxoutf + (size_t)4 * NHW * 384 + (size_t)hwA * 384;
        const f16* cbB = ctxoutf + (size_t)4 * NHW * 384 + (size_t)hwB * 384;
        {
            f16x8 aA = *(const f16x8*)&zS[0][lr][lqw * 8];
            f16x8 aB = *(const f16x8*)&zS[1][lr][lqw * 8];
            #pragma unroll
            for (int t = 0; t < 2; ++t) {
                int n = (nt0 + t) * 16 + lr;
                float thA = (float)cbA[n];
                float thB = (float)cbB[n];
                f32x4 cA = {thA, thA, thA, thA};
                f32x4 cB = {thB, thB, thB, thB};
                cA = __builtin_amdgcn_mfma_f32_16x16x32_f16(aA, B[t], cA, 0, 0, 0);
                cB = __builtin_amdgcn_mfma_f32_16x16x32_f16(aB, B[t], cB, 0, 0, 0);
                #pragma unroll
                for (int r = 0; r < 4; ++r) {
                    tRA[t][r] = cA[r];
                    tRB[t][r] = cB[r];
                    tS[0][lqw * 4 + r][n] = (f16)fmaxf(cA[r], 0.f);
                    tS[1][lqw * 4 + r][n] = (f16)fmaxf(cB[r], 0.f);
                }
            }
            load8(mW1f, nt0, l, B);
        }
        barrier_lgkm();
        #pragma unroll
        for (int blk = 0; blk < 2; ++blk) {
            {
                f32x4 aA0 = vzero, aA1 = vzero, aB0 = vzero, aB1 = vzero;
                gemm16<136>(tS[0], tS[1], lr, lqw, B, aA0, aA1, aB0, aB1);
                load8(mW2f + blk * 16384, nt0, l, B);
                const float* bb1p = made_bb1 + blk * 128;
                float bi0 = bb1p[(nt0 + 0) * 16 + lr];
                float bi1 = bb1p[(nt0 + 1) * 16 + lr];
                #pragma unroll
                for (int r = 0; r < 4; ++r) {
                    uS[0][lqw * 4 + r][(nt0 + 0) * 16 + lr] = (f16)fmaxf(aA0[r] + bi0, 0.f);
                    uS[0][lqw * 4 + r][(nt0 + 1) * 16 + lr] = (f16)fmaxf(aA1[r] + bi1, 0.f);
                    uS[1][lqw * 4 + r][(nt0 + 0) * 16 + lr] = (f16)fmaxf(aB0[r] + bi0, 0.f);
                    uS[1][lqw * 4 + r][(nt0 + 1) * 16 + lr] = (f16)fmaxf(aB1[r] + bi1, 0.f);
                }
            }
            barrier_lgkm();
            {
                f32x4 aA0 = vzero, aA1 = vzero, aB0 = vzero, aB1 = vzero;
                gemm16<200>(uS[0], uS[1], lr, lqw, B, aA0, aA1, aB0, aB1);
                if (blk == 0) load8(mW1f + 16384, nt0, l, B);
                const float* bb2p = made_bb2 + blk * 128;
                float bi0 = bb2p[(nt0 + 0) * 16 + lr];
                float bi1 = bb2p[(nt0 + 1) * 16 + lr];
                float gA0 = (float)cbA[128 + blk * 128 + (nt0 + 0) * 16 + lr];
                float gA1 = (float)cbA[128 + blk * 128 + (nt0 + 1) * 16 + lr];
                float gB0 = (float)cbB[128 + blk * 128 + (nt0 + 0) * 16 + lr];
                float gB1 = (float)cbB[128 + blk * 128 + (nt0 + 1) * 16 + lr];
                #pragma unroll
                for (int r = 0; r < 4; ++r) {
                    tRA[0][r] += (aA0[r] + bi0) * gA0;
                    tRA[1][r] += (aA1[r] + bi1) * gA1;
                    tRB[0][r] += (aB0[r] + bi0) * gB0;
                    tRB[1][r] += (aB1[r] + bi1) * gB1;
                    if (blk == 0) {
                        tS[0][lqw * 4 + r][(nt0 + 0) * 16 + lr] = (f16)fmaxf(tRA[0][r], 0.f);
                        tS[0][lqw * 4 + r][(nt0 + 1) * 16 + lr] = (f16)fmaxf(tRA[1][r], 0.f);
                        tS[1][lqw * 4 + r][(nt0 + 0) * 16 + lr] = (f16)fmaxf(tRB[0][r], 0.f);
                        tS[1][lqw * 4 + r][(nt0 + 1) * 16 + lr] = (f16)fmaxf(tRB[1][r], 0.f);
                    } else {
                        tS[0][lqw * 4 + r][(nt0 + 0) * 16 + lr] = (f16)tRA[0][r];
                        tS[0][lqw * 4 + r][(nt0 + 1) * 16 + lr] = (f16)tRA[1][r];
                        tS[1][lqw * 4 + r][(nt0 + 0) * 16 + lr] = (f16)tRB[0][r];
                        tS[1][lqw * 4 + r][(nt0 + 1) * 16 + lr] = (f16)tRB[1][r];
                    }
                }
            }
            barrier_lgkm();
        }
        // MADE Wout: waves 0-1 -> tile 0 (nt=w), waves 2-3 -> tile 1 (nt=w-2)
        {
            const int t2 = w >> 1, nt = w & 1;
            f32x4 po = vzero;
            #pragma unroll
            for (int ks = 0; ks < 4; ++ks) {
                f16x8 a = *(const f16x8*)&tS[t2][lr][ks * 32 + lqw * 8];
                f16x8 b = *(const f16x8*)(mWoutf + nt * 2048 + ks * 512 + l * 8);
                po = __builtin_amdgcn_mfma_f32_16x16x32_f16(a, b, po, 0, 0, 0);
            }
            int n = nt * 16 + lr;
            float bias = made_bout[n];
            #pragma unroll
            for (int r = 0; r < 4; ++r)
                uS[t2][lqw * 4 + r][n] = (f16)(po[r] + bias);
        }
    }
    barrier_lgkm();
    // ---- Gaussian head (both tiles) ----
    {
        const int rw = tid >> 4, d = tid & 15;
        #pragma unroll
        for (int t2 = 0; t2 < 2; ++t2) {
            const int gm = m0 + t2 * 16 + rw, hw = gm >> 2, b = gm & 3;
            float ar0 = (float)uS[t2][rw][2 * d];
            float ar1 = (float)uS[t2][rw][2 * d + 1];
            float s = softplusf(ar0) + 0.001f;
            float zn = s * zO[t2][rw][d] + ar1;
            float ls   = ehw[(size_t)hw * 32 + 16 + d];
            float mean = ehw[(size_t)hw * 32 + d];
            float diff = (zn - mean) * fexpf(-ls);
            float g = flogf(s) - ls - 0.5f * diff * diff + ldS[t2][d][rw];
            g += __shfl_xor(g, 1);
            g += __shfl_xor(g, 2);
            g += __shfl_xor(g, 4);
            g += __shfl_xor(g, 8);
            if (d == 0)
                out[(size_t)b * NHW + hw] = g + luc0 - 14.703016531274762f;
        }
    }
}

extern "C" void kernel_launch(void* const* d_in, const int* in_sizes, int n_in,
                              void* d_out, int out_size, void* d_ws, size_t ws_size,
                              hipStream_t stream) {
    (void)in_sizes; (void)n_in; (void)out_size; (void)ws_size;
    const float* x         = (const float*)d_in[0];
    const float* made_W0   = (const float*)d_in[1];
    const float* made_b0   = (const float*)d_in[2];
    const float* made_ctxW = (const float*)d_in[3];
    const float* made_ctxb = (const float*)d_in[4];
    const float* made_bW1  = (const float*)d_in[5];
    const float* made_bb1  = (const float*)d_in[6];
    const float* made_bW2  = (const float*)d_in[7];
    const float* made_bb2  = (const float*)d_in[8];
    const float* made_bCW  = (const float*)d_in[9];
    const float* made_bCb  = (const float*)d_in[10];
    const float* made_Wout = (const float*)d_in[11];
    const float* made_bout = (const float*)d_in[12];
    const float* sp_Win    = (const float*)d_in[13];
    const float* sp_bin    = (const float*)d_in[14];
    const float* sp_bW1    = (const float*)d_in[15];
    const float* sp_bb1    = (const float*)d_in[16];
    const float* sp_bW2    = (const float*)d_in[17];
    const float* sp_bb2    = (const float*)d_in[18];
    const float* sp_bCW    = (const float*)d_in[19];
    const float* sp_bCb    = (const float*)d_in[20];
    const float* sp_Wout   = (const float*)d_in[21];
    const float* sp_bout   = (const float*)d_in[22];
    const float* sp_uw     = (const float*)d_in[23];
    const float* sp_uh     = (const float*)d_in[24];
    const float* sp_ud     = (const float*)d_in[25];
    const float* lu_lower  = (const float*)d_in[26];
    const float* lu_upper  = (const float*)d_in[27];
    const float* lu_udiag  = (const float*)d_in[28];
    const float* lu_bias   = (const float*)d_in[29];
    const int*   lu_perm   = (const int*)d_in[30];
    const float* enc_W1    = (const float*)d_in[31];
    const float* enc_b1    = (const float*)d_in[32];
    const float* enc_W2    = (const float*)d_in[33];
    const float* enc_b2    = (const float*)d_in[34];
    float* out = (float*)d_out;

    float* ws      = (float*)d_ws;
    float* z       = ws;                               // 36864*16
    float* ehw     = z       + (size_t)NROWS * 16;     // 9216*32
    float* cpb     = ehw     + (size_t)NHW * 32;       // 5*384
    float* epb     = cpb     + 5 * 384;                // 160 (pad 192)
    float* idk     = epb     + 192;                    // 4*8*48
    float* beff    = idk     + 1536;                   // 4*128
    float* luc     = beff    + 512;                    // 1 (pad 16)
    f16*   ctxoutf = (f16*)(luc + 16);                 // 5*9216*384 f16
    f16*   fW1f    = ctxoutf + (size_t)5 * NHW * 384;  // 8*16384
    f16*   fW2f    = fW1f    + 8 * 16384;              // 8*16384
    f16*   mW1f    = fW2f    + 8 * 16384;              // 2*16384
    f16*   mW2f    = mW1f    + 2 * 16384;              // 2*16384
    f16*   fWoutf  = mW2f    + 2 * 16384;              // 4*24576
    f16*   mWoutf  = fWoutf  + 4 * 24576;              // 4096
    f16*   weffF   = mWoutf  + 4096;                   // 4*4096
    f16*   mlutF   = weffF   + 4 * 4096;               // 4*512
    f16*   minf    = mlutF   + 4 * 512;                // 4096
    f16*   encW1f  = minf    + 4096;                   // 16384
    f16*   encW2f  = encW1f  + 16384;                  // 4096
    f16*   cfrag   = encW2f  + 4096;                   // 5*49152

    dim3 B(256);
    setup_kernel<<<5124, B, 0, stream>>>(
        x,
        sp_bW1, sp_bW2, made_bW1, made_bW2, sp_Wout, made_Wout, sp_Win, made_W0,
        sp_bCW, made_ctxW, made_bCW, sp_bin, sp_bCb, made_ctxb, made_b0, made_bCb,
        enc_W1, enc_b1, enc_W2, enc_b2,
        sp_uw, sp_uh, sp_ud, lu_lower, lu_upper, lu_udiag, lu_bias, lu_perm,
        z,
        fW1f, fW2f, mW1f, mW2f, fWoutf, mWoutf, minf, cfrag, cpb,
        encW1f, encW2f, epb,
        weffF, mlutF, beff, idk, luc);

    ctx_mfma<<<dim3(576, 3), B, 0, stream>>>(cfrag, cpb, encW1f, encW2f, epb,
                                             ctxoutf, ehw);

    mega_all<<<1152, B, 0, stream>>>(z, ctxoutf, weffF, mlutF, beff, minf,
                                     fW1f, fW2f, mW1f, mW2f, fWoutf, mWoutf,
                                     sp_bb1, sp_bb2, made_bb1, made_bb2,
                                     sp_bout, made_bout,
                                     lu_bias, idk, luc, ehw, out);
}